// Round 3
// baseline (7597.437 us; speedup 1.0000x reference)
//
#include <hip/hip_runtime.h>
#include <hip/hip_bf16.h>

typedef __hip_bfloat16 bf16;

// Problem constants (fixed by setup_inputs)
#define NBATCH 8
#define LTOK   576      // 24*24 patches
#define NT     4608     // NBATCH*LTOK tokens
#define CW     768      // model width
#define NH     12
#define HDIM   64
#define DEPTH  4
#define MLPW   3072
#define GRIDP  24       // patches per side
#define IMGS   384

static __device__ __forceinline__ float ldf(const float* p){ return *p; }
static __device__ __forceinline__ float ldf(const bf16* p){ return __bfloat162float(*p); }
static __device__ __forceinline__ void  stf(float* p, float v){ *p = v; }
static __device__ __forceinline__ void  stf(bf16* p, float v){ *p = __float2bfloat16(v); }

// load 64 contiguous elements into fp32 regs (vectorized per type)
static __device__ __forceinline__ void loadrow64(const float* p, float* d){
    #pragma unroll
    for (int i = 0; i < 16; ++i){
        float4 t = ((const float4*)p)[i];
        d[4*i] = t.x; d[4*i+1] = t.y; d[4*i+2] = t.z; d[4*i+3] = t.w;
    }
}
static __device__ __forceinline__ void loadrow64(const bf16* p, float* d){
    #pragma unroll
    for (int i = 0; i < 8; ++i){
        float4 t = ((const float4*)p)[i];           // 8 bf16
        const bf16* b = (const bf16*)&t;
        #pragma unroll
        for (int j = 0; j < 8; ++j) d[8*i+j] = __bfloat162float(b[j]);
    }
}

// ---------------- RoPE cache: cos_x,sin_x,cos_y,sin_y each [576][16] fp32 ----
__global__ void rope_cache_kernel(float* __restrict__ rc){
    int idx = blockIdx.x*256 + threadIdx.x;
    if (idx >= LTOK*16) return;
    int l = idx >> 4, f = idx & 15;
    int py = l / GRIDP, px = l % GRIDP;
    float u = (px + 0.5f) / (float)GRIDP;
    float v = (py + 0.5f) / (float)GRIDP;
    float fr = (float)f / (15.0f + 1e-9f);
    float inv = expf(-fr * 9.210340371976184f);   // 10000^-fr
    float sx, cx, sy, cy;
    sincosf(u * inv, &sx, &cx);
    sincosf(v * inv, &sy, &cy);
    rc[idx]              = cx;   // cos_x
    rc[idx + 9216]       = sx;   // sin_x
    rc[idx + 18432]      = cy;   // cos_y
    rc[idx + 27648]      = sy;   // sin_y
}

// ---------------- patch gather: image (8,384,384,3) f32 -> patches (4608,768)
template<typename TO>
__global__ void patch_gather(const float* __restrict__ img, TO* __restrict__ p){
    int idx = blockIdx.x*256 + threadIdx.x;        // NT*768 total, exact
    int t = idx / CW, kk = idx % CW;
    int n = t / LTOK, l = t % LTOK;
    int py = l / GRIDP, px = l % GRIDP;
    int i = kk / 48, r = kk % 48, j = r / 3, c = r % 3;
    stf(p + idx, img[((size_t)(n*IMGS + py*16 + i)*IMGS + px*16 + j)*3 + c]);
}

// ---------------- GEMM: C = A * B + bias, fp32 accumulation
// EPI: 0 = store, 1 = C += result (residual), 2 = gelu(result). bias may be null.
static __device__ __forceinline__ float gelu_tanh(float x){
    float x3 = x*x*x;
    return 0.5f*x*(1.0f + tanhf(0.7978845608028654f*(x + 0.044715f*x3)));
}

template<typename TA, typename TC, int EPI>
__global__ __launch_bounds__(256) void gemm_k(const TA* __restrict__ A, int lda,
                                              const float* __restrict__ B, int ldb,
                                              const float* __restrict__ bias,
                                              TC* __restrict__ C, int ldc, int K){
    __shared__ __align__(16) float As[16][64+4];   // [k][m]
    __shared__ __align__(16) float Bs[16][64+4];   // [k][n]
    const int tid = threadIdx.x;
    const int tx = tid & 15, ty = tid >> 4;
    const int rowT = blockIdx.y * 64;
    const int colT = blockIdx.x * 64;
    float acc[4][4] = {};
    for (int k0 = 0; k0 < K; k0 += 16){
        #pragma unroll
        for (int i = 0; i < 4; ++i){
            int li = i*256 + tid;
            int m = li >> 4, kk = li & 15;
            As[kk][m] = ldf(A + (size_t)(rowT + m)*lda + k0 + kk);
        }
        #pragma unroll
        for (int i = 0; i < 4; ++i){
            int li = i*256 + tid;
            int kk = li >> 6, nn = li & 63;
            Bs[kk][nn] = B[(size_t)(k0 + kk)*ldb + colT + nn];
        }
        __syncthreads();
        #pragma unroll
        for (int kk = 0; kk < 16; ++kk){
            const float4 a = *(const float4*)&As[kk][ty*4];
            const float4 b = *(const float4*)&Bs[kk][tx*4];
            acc[0][0] += a.x*b.x; acc[0][1] += a.x*b.y; acc[0][2] += a.x*b.z; acc[0][3] += a.x*b.w;
            acc[1][0] += a.y*b.x; acc[1][1] += a.y*b.y; acc[1][2] += a.y*b.z; acc[1][3] += a.y*b.w;
            acc[2][0] += a.z*b.x; acc[2][1] += a.z*b.y; acc[2][2] += a.z*b.z; acc[2][3] += a.z*b.w;
            acc[3][0] += a.w*b.x; acc[3][1] += a.w*b.y; acc[3][2] += a.w*b.z; acc[3][3] += a.w*b.w;
        }
        __syncthreads();
    }
    const int rowB = rowT + ty*4;
    const int colB = colT + tx*4;
    float bb0 = 0.f, bb1 = 0.f, bb2 = 0.f, bb3 = 0.f;
    if (bias){
        bb0 = bias[colB+0]; bb1 = bias[colB+1];
        bb2 = bias[colB+2]; bb3 = bias[colB+3];
    }
    #pragma unroll
    for (int i = 0; i < 4; ++i){
        TC* cp = C + (size_t)(rowB + i)*ldc + colB;
        float r0 = acc[i][0] + bb0, r1 = acc[i][1] + bb1;
        float r2 = acc[i][2] + bb2, r3 = acc[i][3] + bb3;
        if (EPI == 2){ r0 = gelu_tanh(r0); r1 = gelu_tanh(r1); r2 = gelu_tanh(r2); r3 = gelu_tanh(r3); }
        if (EPI == 1){ r0 += ldf(cp+0); r1 += ldf(cp+1); r2 += ldf(cp+2); r3 += ldf(cp+3); }
        stf(cp+0, r0); stf(cp+1, r1); stf(cp+2, r2); stf(cp+3, r3);
    }
}

// ---------------- LayerNorm over 768, one block per token
template<typename T>
__global__ __launch_bounds__(256) void ln_kernel(const T* __restrict__ x,
                                                 const float* __restrict__ sc,
                                                 const float* __restrict__ bs,
                                                 T* __restrict__ y){
    const int t = blockIdx.x, tid = threadIdx.x;
    const T* xr = x + (size_t)t*CW;
    float v0 = ldf(xr+tid), v1 = ldf(xr+tid+256), v2 = ldf(xr+tid+512);
    __shared__ float red[256];
    red[tid] = v0 + v1 + v2; __syncthreads();
    for (int off = 128; off; off >>= 1){ if (tid < off) red[tid] += red[tid+off]; __syncthreads(); }
    float m = red[0] * (1.0f/768.0f);
    __syncthreads();
    float d0 = v0-m, d1 = v1-m, d2 = v2-m;
    red[tid] = d0*d0 + d1*d1 + d2*d2; __syncthreads();
    for (int off = 128; off; off >>= 1){ if (tid < off) red[tid] += red[tid+off]; __syncthreads(); }
    float rs = rsqrtf(red[0]*(1.0f/768.0f) + 1e-6f);
    T* yr = y + (size_t)t*CW;
    stf(yr+tid,     d0*rs*sc[tid]     + bs[tid]);
    stf(yr+tid+256, d1*rs*sc[tid+256] + bs[tid+256]);
    stf(yr+tid+512, d2*rs*sc[tid+512] + bs[tid+512]);
}

// ---------------- RoPE apply (in place, token-major (NT, 12*64))
template<typename T>
__global__ void rope_apply(T* __restrict__ t, const float* __restrict__ rc){
    int idx = blockIdx.x*256 + threadIdx.x;        // NT*12*32 exact
    int tok = idx / 384;
    int r = idx % 384;
    int hh = r >> 5, p = r & 31;
    int l = tok % LTOK;
    float c, s;
    if (p < 16){ c = rc[l*16 + p];            s = rc[9216 + l*16 + p]; }
    else       { c = rc[18432 + l*16 + p-16]; s = rc[27648 + l*16 + p-16]; }
    T* pp = t + (size_t)tok*CW + hh*64 + 2*p;
    float x = ldf(pp), y = ldf(pp+1);
    stf(pp,   x*c - y*s);
    stf(pp+1, x*s + y*c);
}

// ---------------- Attention: block per (q-tile of 16, head, batch)
template<typename T>
__global__ __launch_bounds__(256) void attn_kernel(const T* __restrict__ q,
                                                   const T* __restrict__ k,
                                                   const T* __restrict__ v,
                                                   T* __restrict__ o){
    __shared__ __align__(16) float sq[16][64];
    __shared__ __align__(16) float scb[16][580];   // 576 + pad(4), rows 16B-aligned
    __shared__ float red[16][17];
    const int tid = threadIdx.x;
    const int q0 = blockIdx.x * 16;
    const int hI = blockIdx.y, nI = blockIdx.z;
    const size_t tokBase = (size_t)nI * LTOK;
    const int off = hI * 64;
    for (int li = tid; li < 1024; li += 256){
        int qi = li >> 6, d = li & 63;
        sq[qi][d] = ldf(q + (tokBase + q0 + qi)*CW + off + d) * 0.125f;
    }
    __syncthreads();
    // scores: each lane caches one K row in fp32 regs, serves 4 q rows
    {
        const int jl = tid & 63, qg = tid >> 6;
        for (int jj = 0; jj < 9; ++jj){
            int j = jj*64 + jl;
            float kv[64];
            loadrow64(k + (tokBase + j)*CW + off, kv);
            #pragma unroll
            for (int tq = 0; tq < 4; ++tq){
                int qi = qg + tq*4;
                const float4* qr = (const float4*)&sq[qi][0];
                float acc = 0.f;
                #pragma unroll
                for (int i = 0; i < 16; ++i){
                    float4 a = qr[i];
                    acc += a.x*kv[4*i] + a.y*kv[4*i+1] + a.z*kv[4*i+2] + a.w*kv[4*i+3];
                }
                scb[qi][j] = acc;
            }
        }
    }
    __syncthreads();
    // softmax per row (16 threads per row)
    {
        const int row = tid >> 4, l16 = tid & 15;
        float mx = -1e30f;
        for (int j = l16; j < 576; j += 16) mx = fmaxf(mx, scb[row][j]);
        red[row][l16] = mx; __syncthreads();
        if (l16 == 0){
            float m = red[row][0];
            #pragma unroll
            for (int i = 1; i < 16; ++i) m = fmaxf(m, red[row][i]);
            red[row][16] = m;
        }
        __syncthreads();
        float m = red[row][16];
        float sum = 0.f;
        for (int j = l16; j < 576; j += 16){
            float e = expf(scb[row][j] - m);
            scb[row][j] = e; sum += e;
        }
        red[row][l16] = sum; __syncthreads();
        if (l16 == 0){
            float s = 0.f;
            #pragma unroll
            for (int i = 0; i < 16; ++i) s += red[row][i];
            red[row][16] = s;
        }
        __syncthreads();
        float inv = 1.0f / red[row][16];
        for (int j = l16; j < 576; j += 16) scb[row][j] *= inv;
    }
    __syncthreads();
    // PV: lane d, 4 q rows per thread
    {
        const int d = tid & 63, qg = tid >> 6;
        float a0=0.f, a1=0.f, a2=0.f, a3=0.f;
        for (int j0 = 0; j0 < 576; j0 += 4){
            const T* vb = v + (tokBase + j0)*CW + off + d;
            float v0 = ldf(vb), v1 = ldf(vb+CW), v2 = ldf(vb+2*CW), v3 = ldf(vb+3*CW);
            float4 p0 = *(const float4*)&scb[qg][j0];
            float4 p1 = *(const float4*)&scb[qg+4][j0];
            float4 p2 = *(const float4*)&scb[qg+8][j0];
            float4 p3 = *(const float4*)&scb[qg+12][j0];
            a0 += p0.x*v0 + p0.y*v1 + p0.z*v2 + p0.w*v3;
            a1 += p1.x*v0 + p1.y*v1 + p1.z*v2 + p1.w*v3;
            a2 += p2.x*v0 + p2.y*v1 + p2.z*v2 + p2.w*v3;
            a3 += p3.x*v0 + p3.y*v1 + p3.z*v2 + p3.w*v3;
        }
        stf(o + (tokBase + q0 + qg   )*CW + off + d, a0);
        stf(o + (tokBase + q0 + qg+4 )*CW + off + d, a1);
        stf(o + (tokBase + q0 + qg+8 )*CW + off + d, a2);
        stf(o + (tokBase + q0 + qg+12)*CW + off + d, a3);
    }
}

// ---------------- final mean over tokens -> f32 out (8,768)
template<typename T>
__global__ void mean_kernel(const T* __restrict__ y, float* __restrict__ out){
    int c = blockIdx.x*256 + threadIdx.x;   // 0..767
    int n = blockIdx.y;
    float s = 0.f;
    for (int l = 0; l < LTOK; ++l) s += ldf(y + ((size_t)n*LTOK + l)*CW + c);
    out[n*CW + c] = s * (1.0f/576.0f);
}

// ---------------- host-side graph (templated on intermediate storage type)
template<typename T>
static void run_net(void* const* d_in, T* x, T* y, T* q, T* k, T* v, T* o, T* h,
                    float* ropeC, float* out, hipStream_t stream){
    const float* image = (const float*)d_in[0];
    const float* convk = (const float*)d_in[1];
    const float* convb = (const float*)d_in[2];
    const float* ln1s  = (const float*)d_in[3];
    const float* ln1b  = (const float*)d_in[4];
    const float* wq    = (const float*)d_in[5];
    const float* bq    = (const float*)d_in[6];
    const float* wk    = (const float*)d_in[7];
    const float* bk    = (const float*)d_in[8];
    const float* wv    = (const float*)d_in[9];
    const float* bv    = (const float*)d_in[10];
    const float* wo    = (const float*)d_in[11];
    const float* bo    = (const float*)d_in[12];
    const float* ln2s  = (const float*)d_in[13];
    const float* ln2b  = (const float*)d_in[14];
    const float* w1    = (const float*)d_in[15];
    const float* b1    = (const float*)d_in[16];
    const float* w2    = (const float*)d_in[17];
    const float* b2    = (const float*)d_in[18];
    const float* lnfs  = (const float*)d_in[19];
    const float* lnfb  = (const float*)d_in[20];

    patch_gather<T><<<(NT*CW)/256, 256, 0, stream>>>(image, y);
    gemm_k<T,T,0><<<dim3(12,72), 256, 0, stream>>>(y, CW, convk, CW, convb, x, CW, CW);

    for (int l = 0; l < DEPTH; ++l){
        ln_kernel<T><<<NT, 256, 0, stream>>>(x, ln1s + l*CW, ln1b + l*CW, y);
        gemm_k<T,T,0><<<dim3(12,72), 256, 0, stream>>>(y, CW, wq + (size_t)l*CW*CW, CW, bq + l*CW, q, CW, CW);
        gemm_k<T,T,0><<<dim3(12,72), 256, 0, stream>>>(y, CW, wk + (size_t)l*CW*CW, CW, bk + l*CW, k, CW, CW);
        gemm_k<T,T,0><<<dim3(12,72), 256, 0, stream>>>(y, CW, wv + (size_t)l*CW*CW, CW, bv + l*CW, v, CW, CW);
        rope_apply<T><<<(NT*384)/256, 256, 0, stream>>>(q, ropeC);
        rope_apply<T><<<(NT*384)/256, 256, 0, stream>>>(k, ropeC);
        attn_kernel<T><<<dim3(LTOK/16, NH, NBATCH), 256, 0, stream>>>(q, k, v, o);
        gemm_k<T,T,1><<<dim3(12,72), 256, 0, stream>>>(o, CW, wo + (size_t)l*CW*CW, CW, bo + l*CW, x, CW, CW);
        ln_kernel<T><<<NT, 256, 0, stream>>>(x, ln2s + l*CW, ln2b + l*CW, y);
        // MLP split into two N/K=1536 halves so h fits in the q..k region
        for (int hf = 0; hf < 2; ++hf){
            gemm_k<T,T,2><<<dim3(24,72), 256, 0, stream>>>(y, CW,
                w1 + (size_t)l*CW*MLPW + hf*1536, MLPW, b1 + l*MLPW + hf*1536, h, 1536, CW);
            gemm_k<T,T,1><<<dim3(12,72), 256, 0, stream>>>(h, 1536,
                w2 + (size_t)l*MLPW*CW + (size_t)hf*1536*CW, CW,
                (hf == 0) ? (b2 + l*CW) : (const float*)nullptr, x, CW, 1536);
        }
    }
    ln_kernel<T><<<NT, 256, 0, stream>>>(x, lnfs, lnfb, y);
    mean_kernel<T><<<dim3(3, NBATCH), 256, 0, stream>>>(y, out);
}

extern "C" void kernel_launch(void* const* d_in, const int* in_sizes, int n_in,
                              void* d_out, int out_size, void* d_ws, size_t ws_size,
                              hipStream_t stream){
    float* out = (float*)d_out;
    float* ws = (float*)d_ws;
    float* ropeC = ws;                               // 36864 floats
    rope_cache_kernel<<<36, 256, 0, stream>>>(ropeC);

    const size_t u = (size_t)NT*CW;                  // elements per (NT,768) buffer
    const size_t needA = (size_t)(36864 + 5*u) * 4;  // fp32 layout: ~70.9 MB
    if (ws_size >= needA){
        float* x = ws + 36864;
        float* y = x + u;
        float* q = y + u;
        float* k = q + u;
        float* v = k + u;
        // o aliases y (ln1-out dead after V-gemm); h (NT*1536) aliases q..k
        run_net<float>(d_in, x, y, q, k, v, /*o=*/y, /*h=*/q, ropeC, out, stream);
    } else {
        bf16* x = (bf16*)(ws + 36864);
        bf16* y = x + u;
        bf16* q = y + u;
        bf16* k = q + u;
        bf16* v = k + u;
        run_net<bf16>(d_in, x, y, q, k, v, /*o=*/y, /*h=*/q, ropeC, out, stream);
    }
}

// Round 4
// 2157.459 us; speedup vs baseline: 3.5215x; 3.5215x over previous
//
#include <hip/hip_runtime.h>
#include <hip/hip_bf16.h>

typedef __hip_bfloat16 bf16;
typedef __bf16 bf16x8 __attribute__((ext_vector_type(8)));
typedef float f32x4  __attribute__((ext_vector_type(4)));

// Problem constants (fixed by setup_inputs)
#define NBATCH 8
#define LTOK   576      // 24*24 patches
#define NT     4608     // NBATCH*LTOK tokens
#define CW     768      // model width
#define NH     12
#define HDIM   64
#define DEPTH  4
#define MLPW   3072
#define GRIDP  24       // patches per side
#define IMGS   384

static __device__ __forceinline__ unsigned bfpair(float a, float b){
    bf16 x = __float2bfloat16(a), y = __float2bfloat16(b);
    return ((unsigned)*(unsigned short*)&y << 16) | *(unsigned short*)&x;
}

// ---------------- RoPE cache: cos_x,sin_x,cos_y,sin_y each [576][16] fp32 ----
__global__ void rope_cache_kernel(float* __restrict__ rc){
    int idx = blockIdx.x*256 + threadIdx.x;
    if (idx >= LTOK*16) return;
    int l = idx >> 4, f = idx & 15;
    int py = l / GRIDP, px = l % GRIDP;
    float u = (px + 0.5f) / (float)GRIDP;
    float v = (py + 0.5f) / (float)GRIDP;
    float fr = (float)f / (15.0f + 1e-9f);
    float inv = expf(-fr * 9.210340371976184f);   // 10000^-fr
    float sx, cx, sy, cy;
    sincosf(u * inv, &sx, &cx);
    sincosf(v * inv, &sy, &cy);
    rc[idx]              = cx;
    rc[idx + 9216]       = sx;
    rc[idx + 18432]      = cy;
    rc[idx + 27648]      = sy;
}

// ---------------- patch gather: image (8,384,384,3) f32 -> patches (4608,768)
__global__ void patch_gather(const float* __restrict__ img, float* __restrict__ p){
    int idx = blockIdx.x*256 + threadIdx.x;
    int t = idx / CW, kk = idx % CW;
    int n = t / LTOK, l = t % LTOK;
    int py = l / GRIDP, px = l % GRIDP;
    int i = kk / 48, r = kk % 48, j = r / 3, c = r % 3;
    p[idx] = img[((size_t)(n*IMGS + py*16 + i)*IMGS + px*16 + j)*3 + c];
}

static __device__ __forceinline__ float gelu_tanh(float x){
    float x3 = x*x*x;
    return 0.5f*x*(1.0f + tanhf(0.7978845608028654f*(x + 0.044715f*x3)));
}

// ---------------- MFMA GEMM: C[M,N] = A[M,K](f32) * B[K,N](f32) + bias
// inputs staged to LDS as bf16; fp32 accumulate. Block tile 64x128, BK=32.
// grid: (N/128, M/64), 256 threads (4 waves; wave w owns cols w*32..w*32+31)
// EPI: 0 store, 1 residual add into C, 2 gelu
template<int EPI>
__global__ __launch_bounds__(256) void gemm_mfma(const float* __restrict__ A, int lda,
                                                 const float* __restrict__ B, int ldb,
                                                 const float* __restrict__ bias,
                                                 float* __restrict__ C, int ldc, int K){
    __shared__ bf16 As[64][40];    // [m][k] rows padded to 80 B
    __shared__ bf16 Bs[128][40];   // [n][k]
    const int tid = threadIdx.x;
    const int l = tid & 63, w = tid >> 6;
    const int quad = l >> 4, lr = l & 15;
    const int rowT = blockIdx.y * 64;
    const int colT = blockIdx.x * 128;

    f32x4 acc[4][2];
    #pragma unroll
    for (int i = 0; i < 4; ++i)
        #pragma unroll
        for (int j = 0; j < 2; ++j)
            acc[i][j] = (f32x4){0.f,0.f,0.f,0.f};

    // staging assignments
    const int am  = tid >> 2;          // 0..63
    const int akq = (tid & 3) * 8;     // 0,8,16,24
    const int bn  = tid & 127;         // 0..127
    const int bkg = (tid >> 7) * 16;   // 0 or 16

    for (int k0 = 0; k0 < K; k0 += 32){
        // A tile 64x32
        {
            const float4* ap = (const float4*)(A + (size_t)(rowT + am)*lda + k0 + akq);
            float4 a0 = ap[0], a1 = ap[1];
            uint4 wv; wv.x = bfpair(a0.x,a0.y); wv.y = bfpair(a0.z,a0.w);
                      wv.z = bfpair(a1.x,a1.y); wv.w = bfpair(a1.z,a1.w);
            *(uint4*)&As[am][akq] = wv;
        }
        // B tile 32x128 -> transposed [n][k]
        {
            float vb[16];
            #pragma unroll
            for (int i = 0; i < 16; ++i)
                vb[i] = B[(size_t)(k0 + bkg + i)*ldb + colT + bn];
            uint4 w0, w1;
            w0.x = bfpair(vb[0],vb[1]);   w0.y = bfpair(vb[2],vb[3]);
            w0.z = bfpair(vb[4],vb[5]);   w0.w = bfpair(vb[6],vb[7]);
            w1.x = bfpair(vb[8],vb[9]);   w1.y = bfpair(vb[10],vb[11]);
            w1.z = bfpair(vb[12],vb[13]); w1.w = bfpair(vb[14],vb[15]);
            *(uint4*)&Bs[bn][bkg]     = w0;
            *(uint4*)&Bs[bn][bkg + 8] = w1;
        }
        __syncthreads();
        bf16x8 af[4], bfv[2];
        #pragma unroll
        for (int i = 0; i < 4; ++i) af[i]  = *(const bf16x8*)&As[i*16 + lr][quad*8];
        #pragma unroll
        for (int j = 0; j < 2; ++j) bfv[j] = *(const bf16x8*)&Bs[w*32 + j*16 + lr][quad*8];
        #pragma unroll
        for (int i = 0; i < 4; ++i)
            #pragma unroll
            for (int j = 0; j < 2; ++j)
                acc[i][j] = __builtin_amdgcn_mfma_f32_16x16x32_bf16(af[i], bfv[j], acc[i][j], 0, 0, 0);
        __syncthreads();
    }

    // epilogue: C[row=quad*4+r][col=lr] per 16x16 tile
    #pragma unroll
    for (int i = 0; i < 4; ++i){
        #pragma unroll
        for (int j = 0; j < 2; ++j){
            const int row = rowT + i*16 + quad*4;
            const int col = colT + w*32 + j*16 + lr;
            const float bb = bias ? bias[col] : 0.f;
            #pragma unroll
            for (int r = 0; r < 4; ++r){
                float val = acc[i][j][r] + bb;
                if (EPI == 2) val = gelu_tanh(val);
                float* cp = C + (size_t)(row + r)*ldc + col;
                if (EPI == 1) val += *cp;
                *cp = val;
            }
        }
    }
}

// ---------------- LayerNorm over 768, one block per token
__global__ __launch_bounds__(256) void ln_kernel(const float* __restrict__ x,
                                                 const float* __restrict__ sc,
                                                 const float* __restrict__ bs,
                                                 float* __restrict__ y){
    const int t = blockIdx.x, tid = threadIdx.x;
    const float* xr = x + (size_t)t*CW;
    float v0 = xr[tid], v1 = xr[tid+256], v2 = xr[tid+512];
    __shared__ float red[256];
    red[tid] = v0 + v1 + v2; __syncthreads();
    for (int off = 128; off; off >>= 1){ if (tid < off) red[tid] += red[tid+off]; __syncthreads(); }
    float m = red[0] * (1.0f/768.0f);
    __syncthreads();
    float d0 = v0-m, d1 = v1-m, d2 = v2-m;
    red[tid] = d0*d0 + d1*d1 + d2*d2; __syncthreads();
    for (int off = 128; off; off >>= 1){ if (tid < off) red[tid] += red[tid+off]; __syncthreads(); }
    float rs = rsqrtf(red[0]*(1.0f/768.0f) + 1e-6f);
    float* yr = y + (size_t)t*CW;
    yr[tid]     = d0*rs*sc[tid]     + bs[tid];
    yr[tid+256] = d1*rs*sc[tid+256] + bs[tid+256];
    yr[tid+512] = d2*rs*sc[tid+512] + bs[tid+512];
}

// ---------------- RoPE apply (in place, fp32, token-major (NT, 12*64))
__global__ void rope_apply(float* __restrict__ t, const float* __restrict__ rc){
    int idx = blockIdx.x*256 + threadIdx.x;        // NT*12*32 exact
    int tok = idx / 384;
    int r = idx % 384;
    int hh = r >> 5, p = r & 31;
    int l = tok % LTOK;
    float c, s;
    if (p < 16){ c = rc[l*16 + p];            s = rc[9216 + l*16 + p]; }
    else       { c = rc[18432 + l*16 + p-16]; s = rc[27648 + l*16 + p-16]; }
    float* pp = t + (size_t)tok*CW + hh*64 + 2*p;
    float x = pp[0], y = pp[1];
    pp[0] = x*c - y*s;
    pp[1] = x*s + y*c;
}

// ---------------- Attention via MFMA: block per (16 q rows, head, batch)
__global__ __launch_bounds__(256) void attn_mfma(const float* __restrict__ q,
                                                 const float* __restrict__ k,
                                                 const float* __restrict__ v,
                                                 float* __restrict__ o){
    __shared__ bf16 Qs[16][72];          // [q][d] bf16, pre-scaled
    __shared__ bf16 KVs[64][72];         // K chunk [key][d]; later V chunk [d][key]
    __shared__ float scb[16][580];       // scores / probs fp32
    __shared__ float red[16][17];
    const int tid = threadIdx.x;
    const int l = tid & 63, w = tid >> 6;
    const int quad = l >> 4, lr = l & 15;
    const int q0 = blockIdx.x * 16;
    const int hI = blockIdx.y, nI = blockIdx.z;
    const size_t tokBase = (size_t)nI * LTOK;
    const int off = hI * 64;

    // stage Q (scaled by 1/8) as bf16
    {
        int qq = tid >> 4, d0 = (tid & 15) * 4;
        float4 t4 = *(const float4*)(q + (tokBase + q0 + qq)*CW + off + d0);
        uint2 wv; wv.x = bfpair(t4.x*0.125f, t4.y*0.125f);
                  wv.y = bfpair(t4.z*0.125f, t4.w*0.125f);
        *(uint2*)&Qs[qq][d0] = wv;
    }
    __syncthreads();

    // scores: 9 chunks of 64 keys; wave w computes key-tile w of each chunk
    for (int c = 0; c < 9; ++c){
        {   // stage K chunk [key][d]
            int key = tid >> 2, dq = (tid & 3) * 16;
            const float4* kp = (const float4*)(k + (tokBase + c*64 + key)*CW + off + dq);
            float4 k0v = kp[0], k1 = kp[1], k2 = kp[2], k3 = kp[3];
            uint4 w0, w1;
            w0.x = bfpair(k0v.x,k0v.y); w0.y = bfpair(k0v.z,k0v.w);
            w0.z = bfpair(k1.x,k1.y);   w0.w = bfpair(k1.z,k1.w);
            w1.x = bfpair(k2.x,k2.y);   w1.y = bfpair(k2.z,k2.w);
            w1.z = bfpair(k3.x,k3.y);   w1.w = bfpair(k3.z,k3.w);
            *(uint4*)&KVs[key][dq]     = w0;
            *(uint4*)&KVs[key][dq + 8] = w1;
        }
        __syncthreads();
        f32x4 sc = (f32x4){0.f,0.f,0.f,0.f};
        #pragma unroll
        for (int h = 0; h < 2; ++h){
            bf16x8 aq = *(const bf16x8*)&Qs[lr][h*32 + quad*8];
            bf16x8 bk = *(const bf16x8*)&KVs[w*16 + lr][h*32 + quad*8];
            sc = __builtin_amdgcn_mfma_f32_16x16x32_bf16(aq, bk, sc, 0, 0, 0);
        }
        int col = c*64 + w*16 + lr;
        #pragma unroll
        for (int r = 0; r < 4; ++r) scb[quad*4 + r][col] = sc[r];
        __syncthreads();
    }

    // softmax per row (16 threads per row), probs left normalized in scb
    {
        const int row = tid >> 4, l16 = tid & 15;
        float mx = -1e30f;
        for (int j = l16; j < 576; j += 16) mx = fmaxf(mx, scb[row][j]);
        red[row][l16] = mx; __syncthreads();
        if (l16 == 0){
            float m = red[row][0];
            #pragma unroll
            for (int i = 1; i < 16; ++i) m = fmaxf(m, red[row][i]);
            red[row][16] = m;
        }
        __syncthreads();
        float m = red[row][16];
        float sum = 0.f;
        for (int j = l16; j < 576; j += 16){
            float e = expf(scb[row][j] - m);
            scb[row][j] = e; sum += e;
        }
        red[row][l16] = sum; __syncthreads();
        if (l16 == 0){
            float s = 0.f;
            #pragma unroll
            for (int i = 0; i < 16; ++i) s += red[row][i];
            red[row][16] = s;
        }
        __syncthreads();
        float inv = 1.0f / red[row][16];
        for (int j = l16; j < 576; j += 16) scb[row][j] *= inv;
    }

    // PV: 9 chunks; V staged transposed [d][key]; wave w owns d-tile w
    f32x4 oacc = (f32x4){0.f,0.f,0.f,0.f};
    for (int c = 0; c < 9; ++c){
        {   // stage V chunk -> Vs[d][key]
            int d = tid & 63, k0v = (tid >> 6) * 16;
            float tv[16];
            #pragma unroll
            for (int i = 0; i < 16; ++i)
                tv[i] = v[(tokBase + c*64 + k0v + i)*CW + off + d];
            uint4 w0, w1;
            w0.x = bfpair(tv[0],tv[1]);   w0.y = bfpair(tv[2],tv[3]);
            w0.z = bfpair(tv[4],tv[5]);   w0.w = bfpair(tv[6],tv[7]);
            w1.x = bfpair(tv[8],tv[9]);   w1.y = bfpair(tv[10],tv[11]);
            w1.z = bfpair(tv[12],tv[13]); w1.w = bfpair(tv[14],tv[15]);
            __syncthreads();               // all reads of previous chunk done
            *(uint4*)&KVs[d][k0v]     = w0;
            *(uint4*)&KVs[d][k0v + 8] = w1;
        }
        __syncthreads();
        #pragma unroll
        for (int h = 0; h < 2; ++h){
            int kb = c*64 + h*32 + quad*8;
            float4 p0 = *(const float4*)&scb[lr][kb];
            float4 p1 = *(const float4*)&scb[lr][kb + 4];
            uint4 pt; pt.x = bfpair(p0.x,p0.y); pt.y = bfpair(p0.z,p0.w);
                      pt.z = bfpair(p1.x,p1.y); pt.w = bfpair(p1.z,p1.w);
            bf16x8 pa = *(const bf16x8*)&pt;
            bf16x8 vb = *(const bf16x8*)&KVs[w*16 + lr][h*32 + quad*8];
            oacc = __builtin_amdgcn_mfma_f32_16x16x32_bf16(pa, vb, oacc, 0, 0, 0);
        }
    }
    #pragma unroll
    for (int r = 0; r < 4; ++r)
        o[(tokBase + q0 + quad*4 + r)*CW + off + w*16 + lr] = oacc[r];
}

// ---------------- final mean over tokens -> f32 out (8,768)
__global__ void mean_kernel(const float* __restrict__ y, float* __restrict__ out){
    int c = blockIdx.x*256 + threadIdx.x;   // 0..767
    int n = blockIdx.y;
    float s = 0.f;
    for (int l = 0; l < LTOK; ++l) s += y[((size_t)n*LTOK + l)*CW + c];
    out[n*CW + c] = s * (1.0f/576.0f);
}

extern "C" void kernel_launch(void* const* d_in, const int* in_sizes, int n_in,
                              void* d_out, int out_size, void* d_ws, size_t ws_size,
                              hipStream_t stream){
    const float* image = (const float*)d_in[0];
    const float* convk = (const float*)d_in[1];
    const float* convb = (const float*)d_in[2];
    const float* ln1s  = (const float*)d_in[3];
    const float* ln1b  = (const float*)d_in[4];
    const float* wq    = (const float*)d_in[5];
    const float* bq    = (const float*)d_in[6];
    const float* wk    = (const float*)d_in[7];
    const float* bk    = (const float*)d_in[8];
    const float* wv    = (const float*)d_in[9];
    const float* bv    = (const float*)d_in[10];
    const float* wo    = (const float*)d_in[11];
    const float* bo    = (const float*)d_in[12];
    const float* ln2s  = (const float*)d_in[13];
    const float* ln2b  = (const float*)d_in[14];
    const float* w1    = (const float*)d_in[15];
    const float* b1    = (const float*)d_in[16];
    const float* w2    = (const float*)d_in[17];
    const float* b2    = (const float*)d_in[18];
    const float* lnfs  = (const float*)d_in[19];
    const float* lnfb  = (const float*)d_in[20];
    float* out = (float*)d_out;

    float* ws    = (float*)d_ws;
    float* ropeC = ws;                       // 36864 floats
    const size_t u = (size_t)NT*CW;
    float* x = ws + 36864;
    float* y = x + u;
    float* q = y + u;
    float* k = q + u;
    float* v = k + u;
    float* o = y;          // ln1-out dead after V gemm
    float* h = q;          // MLP hidden (NT x 1536) overlays q,k

    rope_cache_kernel<<<36, 256, 0, stream>>>(ropeC);
    patch_gather<<<(NT*CW)/256, 256, 0, stream>>>(image, y);
    gemm_mfma<0><<<dim3(6,72), 256, 0, stream>>>(y, CW, convk, CW, convb, x, CW, CW);

    for (int l = 0; l < DEPTH; ++l){
        ln_kernel<<<NT, 256, 0, stream>>>(x, ln1s + l*CW, ln1b + l*CW, y);
        gemm_mfma<0><<<dim3(6,72), 256, 0, stream>>>(y, CW, wq + (size_t)l*CW*CW, CW, bq + l*CW, q, CW, CW);
        gemm_mfma<0><<<dim3(6,72), 256, 0, stream>>>(y, CW, wk + (size_t)l*CW*CW, CW, bk + l*CW, k, CW, CW);
        gemm_mfma<0><<<dim3(6,72), 256, 0, stream>>>(y, CW, wv + (size_t)l*CW*CW, CW, bv + l*CW, v, CW, CW);
        rope_apply<<<(NT*384)/256, 256, 0, stream>>>(q, ropeC);
        rope_apply<<<(NT*384)/256, 256, 0, stream>>>(k, ropeC);
        attn_mfma<<<dim3(LTOK/16, NH, NBATCH), 256, 0, stream>>>(q, k, v, o);
        gemm_mfma<1><<<dim3(6,72), 256, 0, stream>>>(o, CW, wo + (size_t)l*CW*CW, CW, bo + l*CW, x, CW, CW);
        ln_kernel<<<NT, 256, 0, stream>>>(x, ln2s + l*CW, ln2b + l*CW, y);
        for (int hf = 0; hf < 2; ++hf){
            gemm_mfma<2><<<dim3(12,72), 256, 0, stream>>>(y, CW,
                w1 + (size_t)l*CW*MLPW + hf*1536, MLPW, b1 + l*MLPW + hf*1536, h, 1536, CW);
            gemm_mfma<1><<<dim3(6,72), 256, 0, stream>>>(h, 1536,
                w2 + (size_t)l*MLPW*CW + (size_t)hf*1536*CW, CW,
                (hf == 0) ? (b2 + l*CW) : (const float*)nullptr, x, CW, 1536);
        }
    }
    ln_kernel<<<NT, 256, 0, stream>>>(x, lnfs, lnfb, y);
    mean_kernel<<<dim3(3, NBATCH), 256, 0, stream>>>(y, out);
}

// Round 5
// 1626.265 us; speedup vs baseline: 4.6717x; 1.3266x over previous
//
#include <hip/hip_runtime.h>
#include <hip/hip_bf16.h>

typedef __hip_bfloat16 bf16;
typedef __bf16 bf16x8 __attribute__((ext_vector_type(8)));
typedef float f32x4  __attribute__((ext_vector_type(4)));

#define NBATCH 8
#define LTOK   576
#define NT     4608
#define CW     768
#define NH     12
#define HDIM   64
#define DEPTH  4
#define MLPW   3072
#define GRIDP  24
#define IMGS   384

static __device__ __forceinline__ unsigned bfpair(float a, float b){
    bf16 x = __float2bfloat16(a), y = __float2bfloat16(b);
    return ((unsigned)*(unsigned short*)&y << 16) | *(unsigned short*)&x;
}
static __device__ __forceinline__ float b2f(bf16 v){ return __bfloat162float(v); }

// ---------------- RoPE cache ----------------
__global__ void rope_cache_kernel(float* __restrict__ rc){
    int idx = blockIdx.x*256 + threadIdx.x;
    if (idx >= LTOK*16) return;
    int l = idx >> 4, f = idx & 15;
    int py = l / GRIDP, px = l % GRIDP;
    float u = (px + 0.5f) / (float)GRIDP;
    float v = (py + 0.5f) / (float)GRIDP;
    float fr = (float)f / (15.0f + 1e-9f);
    float inv = expf(-fr * 9.210340371976184f);
    float sx, cx, sy, cy;
    sincosf(u * inv, &sx, &cx);
    sincosf(v * inv, &sy, &cy);
    rc[idx]         = cx;
    rc[idx + 9216]  = sx;
    rc[idx + 18432] = cy;
    rc[idx + 27648] = sy;
}

// ---------------- patch gather: f32 image -> bf16 patches (4608,768)
__global__ void patch_gather(const float* __restrict__ img, bf16* __restrict__ p){
    int idx = blockIdx.x*256 + threadIdx.x;
    int t = idx / CW, kk = idx % CW;
    int n = t / LTOK, l = t % LTOK;
    int py = l / GRIDP, px = l % GRIDP;
    int i = kk / 48, r = kk % 48, j = r / 3, c = r % 3;
    p[idx] = __float2bfloat16(img[((size_t)(n*IMGS + py*16 + i)*IMGS + px*16 + j)*3 + c]);
}

// ---------------- weight transpose+convert: f32 [K][N] -> bf16 [N][K]
__global__ __launch_bounds__(256) void wtrans(const float* __restrict__ in, bf16* __restrict__ out,
                                              int K, int N){
    __shared__ float t[32][33];
    const int n0 = blockIdx.x*32, k0 = blockIdx.y*32;
    const int tx = threadIdx.x & 31, ty = threadIdx.x >> 5;  // ty 0..7
    #pragma unroll
    for (int r = 0; r < 4; ++r)
        t[ty + 8*r][tx] = in[(size_t)(k0 + ty + 8*r)*N + n0 + tx];
    __syncthreads();
    #pragma unroll
    for (int r = 0; r < 4; ++r)
        out[(size_t)(n0 + ty + 8*r)*K + k0 + tx] = __float2bfloat16(t[tx][ty + 8*r]);
}

static __device__ __forceinline__ float gelu_tanh(float x){
    float x3 = x*x*x;
    return 0.5f*x*(1.0f + tanhf(0.7978845608028654f*(x + 0.044715f*x3)));
}

// ---------------- MFMA GEMM, B pre-transposed bf16 [N][K]
// A bf16 [M][K]. Tile M128 x N64, BK=64, XOR-swizzled LDS.
// EPI: 0 = bf16 store, 1 = fp32 residual add, 2 = bf16 gelu, 3 = fp32 store
template<int EPI, typename TC>
__global__ __launch_bounds__(256) void gemm_bt(const bf16* __restrict__ A, int lda,
                                               const bf16* __restrict__ B, int ldb,
                                               const float* __restrict__ bias,
                                               TC* __restrict__ C, int ldc, int K){
    __shared__ bf16 As[128*64];   // row r at r*64; chunk c (8 bf16) stored at (c^(r&7))
    __shared__ bf16 Bs[64*64];
    const int tid = threadIdx.x;
    const int w = tid >> 6, l = tid & 63;
    const int quad = l >> 4, lr = l & 15;
    const int wm = w & 1, wn = w >> 1;
    const int rowT = blockIdx.y * 128;
    const int colT = blockIdx.x * 64;

    f32x4 acc[4][2];
    #pragma unroll
    for (int i = 0; i < 4; ++i)
        #pragma unroll
        for (int j = 0; j < 2; ++j) acc[i][j] = (f32x4){0.f,0.f,0.f,0.f};

    for (int k0 = 0; k0 < K; k0 += 64){
        #pragma unroll
        for (int i = 0; i < 4; ++i){      // A: 128 rows x 8 chunks
            int g = i*256 + tid, r = g >> 3, c = g & 7;
            uint4 val = *(const uint4*)(A + (size_t)(rowT + r)*lda + k0 + c*8);
            *(uint4*)(As + r*64 + ((c ^ (r & 7))*8)) = val;
        }
        #pragma unroll
        for (int i = 0; i < 2; ++i){      // B: 64 rows x 8 chunks
            int g = i*256 + tid, r = g >> 3, c = g & 7;
            uint4 val = *(const uint4*)(B + (size_t)(colT + r)*ldb + k0 + c*8);
            *(uint4*)(Bs + r*64 + ((c ^ (r & 7))*8)) = val;
        }
        __syncthreads();
        #pragma unroll
        for (int kh = 0; kh < 2; ++kh){
            bf16x8 af[4], bfr[2];
            #pragma unroll
            for (int i = 0; i < 4; ++i){
                int r = wm*64 + i*16 + lr;
                af[i] = *(const bf16x8*)(As + r*64 + (((kh*4 + quad) ^ (r & 7))*8));
            }
            #pragma unroll
            for (int j = 0; j < 2; ++j){
                int r = wn*32 + j*16 + lr;
                bfr[j] = *(const bf16x8*)(Bs + r*64 + (((kh*4 + quad) ^ (r & 7))*8));
            }
            #pragma unroll
            for (int i = 0; i < 4; ++i)
                #pragma unroll
                for (int j = 0; j < 2; ++j)
                    acc[i][j] = __builtin_amdgcn_mfma_f32_16x16x32_bf16(af[i], bfr[j], acc[i][j], 0, 0, 0);
        }
        __syncthreads();
    }

    #pragma unroll
    for (int i = 0; i < 4; ++i){
        #pragma unroll
        for (int j = 0; j < 2; ++j){
            const int row = rowT + wm*64 + i*16 + quad*4;
            const int col = colT + wn*32 + j*16 + lr;
            const float bb = bias ? bias[col] : 0.f;
            #pragma unroll
            for (int r = 0; r < 4; ++r){
                float val = acc[i][j][r] + bb;
                TC* cp = C + (size_t)(row + r)*ldc + col;
                if (EPI == 2) val = gelu_tanh(val);
                if (EPI == 1) val += *(float*)cp;
                if (EPI == 0 || EPI == 2) *(bf16*)cp = __float2bfloat16(val);
                else                      *(float*)cp = val;
            }
        }
    }
}

// ---------------- LayerNorm: fp32 x -> bf16 y
__global__ __launch_bounds__(256) void ln_kernel(const float* __restrict__ x,
                                                 const float* __restrict__ sc,
                                                 const float* __restrict__ bs,
                                                 bf16* __restrict__ y){
    const int t = blockIdx.x, tid = threadIdx.x;
    const float* xr = x + (size_t)t*CW;
    float v0 = xr[tid], v1 = xr[tid+256], v2 = xr[tid+512];
    __shared__ float red[256];
    red[tid] = v0 + v1 + v2; __syncthreads();
    for (int off = 128; off; off >>= 1){ if (tid < off) red[tid] += red[tid+off]; __syncthreads(); }
    float m = red[0] * (1.0f/768.0f);
    __syncthreads();
    float d0 = v0-m, d1 = v1-m, d2 = v2-m;
    red[tid] = d0*d0 + d1*d1 + d2*d2; __syncthreads();
    for (int off = 128; off; off >>= 1){ if (tid < off) red[tid] += red[tid+off]; __syncthreads(); }
    float rs = rsqrtf(red[0]*(1.0f/768.0f) + 1e-6f);
    bf16* yr = y + (size_t)t*CW;
    yr[tid]     = __float2bfloat16(d0*rs*sc[tid]     + bs[tid]);
    yr[tid+256] = __float2bfloat16(d1*rs*sc[tid+256] + bs[tid+256]);
    yr[tid+512] = __float2bfloat16(d2*rs*sc[tid+512] + bs[tid+512]);
}

// ---------------- RoPE apply on bf16 (in place)
__global__ void rope_apply(bf16* __restrict__ t, const float* __restrict__ rc){
    int idx = blockIdx.x*256 + threadIdx.x;        // NT*384 exact
    int tok = idx / 384;
    int r = idx % 384;
    int hh = r >> 5, p = r & 31;
    int l = tok % LTOK;
    float c, s;
    if (p < 16){ c = rc[l*16 + p];            s = rc[9216 + l*16 + p]; }
    else       { c = rc[18432 + l*16 + p-16]; s = rc[27648 + l*16 + p-16]; }
    bf16* pp = t + (size_t)tok*CW + hh*64 + 2*p;
    unsigned u = *(unsigned*)pp;
    bf16 lo = *(bf16*)&u; unsigned short hi16 = u >> 16; bf16 hi = *(bf16*)&hi16;
    float x = b2f(lo), y = b2f(hi);
    *(unsigned*)pp = bfpair(x*c - y*s, x*s + y*c);
}

// ---------------- V transpose: v [tok][CW] bf16 -> vT [(n,h)][d=64][576]
__global__ __launch_bounds__(256) void vtrans(const bf16* __restrict__ v, bf16* __restrict__ vT){
    __shared__ bf16 tile[64][72];
    const int t0 = blockIdx.x*64, hI = blockIdx.y, nI = blockIdx.z;
    const size_t base = ((size_t)nI*LTOK + t0)*CW + hI*64;
    const int tid = threadIdx.x;
    #pragma unroll
    for (int i = 0; i < 2; ++i){
        int g = i*256 + tid, r = g >> 3, c = g & 7;
        *(uint4*)&tile[r][c*8] = *(const uint4*)(v + base + (size_t)r*CW + c*8);
    }
    __syncthreads();
    const size_t obase = ((size_t)(nI*NH + hI)*64)*576 + t0;
    #pragma unroll
    for (int i = 0; i < 2; ++i){
        int g = i*256 + tid, d = g >> 3, c = g & 7;
        bf16 tmp[8];
        #pragma unroll
        for (int j = 0; j < 8; ++j) tmp[j] = tile[c*8 + j][d];
        *(uint4*)(vT + obase + (size_t)d*576 + c*8) = *(uint4*)tmp;
    }
}

// ---------------- Attention: block per (16 q rows, head, batch), bf16 in/out
__global__ __launch_bounds__(256) void attn_mfma(const bf16* __restrict__ q,
                                                 const bf16* __restrict__ k,
                                                 const bf16* __restrict__ vT,
                                                 bf16* __restrict__ o){
    __shared__ bf16 Qs[16*80];           // [q][d] pitch 80
    __shared__ bf16 Ks[64*80];           // K chunk [key][d] ; later V chunk [d][key]
    __shared__ float scb[16][580];
    __shared__ float red[16][17];
    const int tid = threadIdx.x;
    const int w = tid >> 6, l = tid & 63;
    const int quad = l >> 4, lr = l & 15;
    const int q0 = blockIdx.x * 16;
    const int hI = blockIdx.y, nI = blockIdx.z;
    const size_t tokBase = (size_t)nI * LTOK;
    const int off = hI * 64;

    if (tid < 128){
        int r = tid >> 3, c = tid & 7;
        *(uint4*)(Qs + r*80 + c*8) = *(const uint4*)(q + (tokBase + q0 + r)*CW + off + c*8);
    }
    __syncthreads();

    // scores
    for (int ch = 0; ch < 9; ++ch){
        #pragma unroll
        for (int i = 0; i < 2; ++i){
            int g = i*256 + tid, r = g >> 3, c = g & 7;
            *(uint4*)(Ks + r*80 + c*8) = *(const uint4*)(k + (tokBase + ch*64 + r)*CW + off + c*8);
        }
        __syncthreads();
        f32x4 sc = (f32x4){0.f,0.f,0.f,0.f};
        #pragma unroll
        for (int kh = 0; kh < 2; ++kh){
            bf16x8 aq = *(const bf16x8*)(Qs + lr*80 + kh*32 + quad*8);
            bf16x8 bk = *(const bf16x8*)(Ks + (w*16 + lr)*80 + kh*32 + quad*8);
            sc = __builtin_amdgcn_mfma_f32_16x16x32_bf16(aq, bk, sc, 0, 0, 0);
        }
        int col = ch*64 + w*16 + lr;
        #pragma unroll
        for (int r = 0; r < 4; ++r) scb[quad*4 + r][col] = sc[r] * 0.125f;
        __syncthreads();
    }

    // softmax per row
    {
        const int row = tid >> 4, l16 = tid & 15;
        float mx = -1e30f;
        for (int j = l16; j < 576; j += 16) mx = fmaxf(mx, scb[row][j]);
        red[row][l16] = mx; __syncthreads();
        if (l16 == 0){
            float m = red[row][0];
            #pragma unroll
            for (int i = 1; i < 16; ++i) m = fmaxf(m, red[row][i]);
            red[row][16] = m;
        }
        __syncthreads();
        float m = red[row][16];
        float sum = 0.f;
        for (int j = l16; j < 576; j += 16){
            float e = expf(scb[row][j] - m);
            scb[row][j] = e; sum += e;
        }
        red[row][l16] = sum; __syncthreads();
        if (l16 == 0){
            float s = 0.f;
            #pragma unroll
            for (int i = 0; i < 16; ++i) s += red[row][i];
            red[row][16] = s;
        }
        __syncthreads();
        float inv = 1.0f / red[row][16];
        for (int j = l16; j < 576; j += 16) scb[row][j] *= inv;
    }

    // PV
    f32x4 oacc = (f32x4){0.f,0.f,0.f,0.f};
    const size_t vbase = ((size_t)(nI*NH + hI)*64)*576;
    for (int ch = 0; ch < 9; ++ch){
        __syncthreads();
        #pragma unroll
        for (int i = 0; i < 2; ++i){
            int g = i*256 + tid, d = g >> 3, c = g & 7;
            *(uint4*)(Ks + d*80 + c*8) = *(const uint4*)(vT + vbase + (size_t)d*576 + ch*64 + c*8);
        }
        __syncthreads();
        #pragma unroll
        for (int kh = 0; kh < 2; ++kh){
            int kb = ch*64 + kh*32 + quad*8;
            float4 p0 = *(const float4*)&scb[lr][kb];
            float4 p1 = *(const float4*)&scb[lr][kb + 4];
            uint4 pt; pt.x = bfpair(p0.x,p0.y); pt.y = bfpair(p0.z,p0.w);
                      pt.z = bfpair(p1.x,p1.y); pt.w = bfpair(p1.z,p1.w);
            bf16x8 pa = *(const bf16x8*)&pt;
            bf16x8 vb = *(const bf16x8*)(Ks + (w*16 + lr)*80 + kh*32 + quad*8);
            oacc = __builtin_amdgcn_mfma_f32_16x16x32_bf16(pa, vb, oacc, 0, 0, 0);
        }
    }
    #pragma unroll
    for (int r = 0; r < 4; ++r)
        o[(tokBase + q0 + quad*4 + r)*CW + off + w*16 + lr] = __float2bfloat16(oacc[r]);
}

// ---------------- final mean over tokens (bf16 y) -> f32 out (8,768)
__global__ void mean_kernel(const bf16* __restrict__ y, float* __restrict__ out){
    int c = blockIdx.x*256 + threadIdx.x;
    int n = blockIdx.y;
    float s = 0.f;
    for (int l = 0; l < LTOK; ++l) s += b2f(y[((size_t)n*LTOK + l)*CW + c]);
    out[n*CW + c] = s * (1.0f/576.0f);
}

extern "C" void kernel_launch(void* const* d_in, const int* in_sizes, int n_in,
                              void* d_out, int out_size, void* d_ws, size_t ws_size,
                              hipStream_t stream){
    const float* image = (const float*)d_in[0];
    const float* convk = (const float*)d_in[1];
    const float* convb = (const float*)d_in[2];
    const float* ln1s  = (const float*)d_in[3];
    const float* ln1b  = (const float*)d_in[4];
    const float* wq    = (const float*)d_in[5];
    const float* bq    = (const float*)d_in[6];
    const float* wk    = (const float*)d_in[7];
    const float* bk    = (const float*)d_in[8];
    const float* wv    = (const float*)d_in[9];
    const float* bv    = (const float*)d_in[10];
    const float* wo    = (const float*)d_in[11];
    const float* bo    = (const float*)d_in[12];
    const float* ln2s  = (const float*)d_in[13];
    const float* ln2b  = (const float*)d_in[14];
    const float* w1    = (const float*)d_in[15];
    const float* b1    = (const float*)d_in[16];
    const float* w2    = (const float*)d_in[17];
    const float* b2    = (const float*)d_in[18];
    const float* lnfs  = (const float*)d_in[19];
    const float* lnfb  = (const float*)d_in[20];
    float* out = (float*)d_out;

    const size_t u = (size_t)NT*CW;          // 3538944
    float* ws    = (float*)d_ws;
    float* ropeC = ws;                       // 36864 f32
    float* x     = ws + 36864;               // fp32 residual
    bf16*  y     = (bf16*)(x + u);           // bf16 region
    bf16*  q     = y + u;
    bf16*  k     = q + u;
    bf16*  v     = k + u;
    bf16*  vT    = v + u;
    bf16*  wring = vT + u;                   // 7077888 bf16 ring
    bf16*  o     = y;                        // alias
    bf16*  h     = q;                        // alias (NT x 1536 over q+k)

    bf16* wqT = wring;
    bf16* wkT = wqT + 589824;
    bf16* wvT = wkT + 589824;
    bf16* woT = wvT + 589824;
    bf16* w1T = woT + 589824;
    bf16* w2T = w1T + 2359296;

    rope_cache_kernel<<<36, 256, 0, stream>>>(ropeC);
    patch_gather<<<(NT*CW)/256, 256, 0, stream>>>(image, y);
    wtrans<<<dim3(24,24), 256, 0, stream>>>(convk, wqT, CW, CW);
    gemm_bt<3,float><<<dim3(12,36), 256, 0, stream>>>(y, CW, wqT, CW, convb, x, CW, CW);

    for (int l = 0; l < DEPTH; ++l){
        wtrans<<<dim3(24,24), 256, 0, stream>>>(wq + (size_t)l*CW*CW, wqT, CW, CW);
        wtrans<<<dim3(24,24), 256, 0, stream>>>(wk + (size_t)l*CW*CW, wkT, CW, CW);
        wtrans<<<dim3(24,24), 256, 0, stream>>>(wv + (size_t)l*CW*CW, wvT, CW, CW);
        wtrans<<<dim3(24,24), 256, 0, stream>>>(wo + (size_t)l*CW*CW, woT, CW, CW);
        wtrans<<<dim3(96,24), 256, 0, stream>>>(w1 + (size_t)l*CW*MLPW, w1T, CW, MLPW);
        wtrans<<<dim3(24,96), 256, 0, stream>>>(w2 + (size_t)l*MLPW*CW, w2T, MLPW, CW);

        ln_kernel<<<NT, 256, 0, stream>>>(x, ln1s + l*CW, ln1b + l*CW, y);
        gemm_bt<0,bf16><<<dim3(12,36), 256, 0, stream>>>(y, CW, wqT, CW, bq + l*CW, q, CW, CW);
        gemm_bt<0,bf16><<<dim3(12,36), 256, 0, stream>>>(y, CW, wkT, CW, bk + l*CW, k, CW, CW);
        gemm_bt<0,bf16><<<dim3(12,36), 256, 0, stream>>>(y, CW, wvT, CW, bv + l*CW, v, CW, CW);
        rope_apply<<<(NT*384)/256, 256, 0, stream>>>(q, ropeC);
        rope_apply<<<(NT*384)/256, 256, 0, stream>>>(k, ropeC);
        vtrans<<<dim3(9, NH, NBATCH), 256, 0, stream>>>(v, vT);
        attn_mfma<<<dim3(LTOK/16, NH, NBATCH), 256, 0, stream>>>(q, k, vT, o);
        gemm_bt<1,float><<<dim3(12,36), 256, 0, stream>>>(o, CW, woT, CW, bo + l*CW, x, CW, CW);
        ln_kernel<<<NT, 256, 0, stream>>>(x, ln2s + l*CW, ln2b + l*CW, y);
        for (int hf = 0; hf < 2; ++hf){
            gemm_bt<2,bf16><<<dim3(24,36), 256, 0, stream>>>(y, CW,
                w1T + (size_t)hf*1536*CW, CW, b1 + l*MLPW + hf*1536, h, 1536, CW);
            gemm_bt<1,float><<<dim3(12,36), 256, 0, stream>>>(h, 1536,
                w2T + hf*1536, MLPW,
                (hf == 0) ? (b2 + l*CW) : (const float*)nullptr, x, CW, 1536);
        }
    }
    ln_kernel<<<NT, 256, 0, stream>>>(x, lnfs, lnfb, y);
    mean_kernel<<<dim3(3, NBATCH), 256, 0, stream>>>(y, out);
}

// Round 6
// 1305.547 us; speedup vs baseline: 5.8193x; 1.2457x over previous
//
#include <hip/hip_runtime.h>
#include <hip/hip_bf16.h>

typedef __hip_bfloat16 bf16;
typedef __bf16 bf16x8 __attribute__((ext_vector_type(8)));
typedef float f32x4  __attribute__((ext_vector_type(4)));

#define NBATCH 8
#define LTOK   576
#define NT     4608
#define CW     768
#define NH     12
#define HDIM   64
#define DEPTH  4
#define MLPW   3072
#define GRIDP  24
#define IMGS   384

static __device__ __forceinline__ unsigned bfpair(float a, float b){
    bf16 x = __float2bfloat16(a), y = __float2bfloat16(b);
    return ((unsigned)*(unsigned short*)&y << 16) | *(unsigned short*)&x;
}
static __device__ __forceinline__ float b2f(bf16 v){ return __bfloat162float(v); }

// ---------------- RoPE cache ----------------
__global__ void rope_cache_kernel(float* __restrict__ rc){
    int idx = blockIdx.x*256 + threadIdx.x;
    if (idx >= LTOK*16) return;
    int l = idx >> 4, f = idx & 15;
    int py = l / GRIDP, px = l % GRIDP;
    float u = (px + 0.5f) / (float)GRIDP;
    float v = (py + 0.5f) / (float)GRIDP;
    float fr = (float)f / (15.0f + 1e-9f);
    float inv = expf(-fr * 9.210340371976184f);
    float sx, cx, sy, cy;
    sincosf(u * inv, &sx, &cx);
    sincosf(v * inv, &sy, &cy);
    rc[idx]         = cx;
    rc[idx + 9216]  = sx;
    rc[idx + 18432] = cy;
    rc[idx + 27648] = sy;
}

// ---------------- patch gather: f32 image -> bf16 patches (4608,768)
__global__ void patch_gather(const float* __restrict__ img, bf16* __restrict__ p){
    int idx = blockIdx.x*256 + threadIdx.x;
    int t = idx / CW, kk = idx % CW;
    int n = t / LTOK, l = t % LTOK;
    int py = l / GRIDP, px = l % GRIDP;
    int i = kk / 48, r = kk % 48, j = r / 3, c = r % 3;
    p[idx] = __float2bfloat16(img[((size_t)(n*IMGS + py*16 + i)*IMGS + px*16 + j)*3 + c]);
}

// ---------------- weight transpose+convert: f32 [K][N] -> bf16 [N][K]
__global__ __launch_bounds__(256) void wtrans(const float* __restrict__ in, bf16* __restrict__ out,
                                              int K, int N){
    __shared__ float t[32][33];
    const int n0 = blockIdx.x*32, k0 = blockIdx.y*32;
    const int tx = threadIdx.x & 31, ty = threadIdx.x >> 5;
    #pragma unroll
    for (int r = 0; r < 4; ++r)
        t[ty + 8*r][tx] = in[(size_t)(k0 + ty + 8*r)*N + n0 + tx];
    __syncthreads();
    #pragma unroll
    for (int r = 0; r < 4; ++r)
        out[(size_t)(n0 + ty + 8*r)*K + k0 + tx] = __float2bfloat16(t[tx][ty + 8*r]);
}

static __device__ __forceinline__ float gelu_tanh(float x){
    float x3 = x*x*x;
    return 0.5f*x*(1.0f + tanhf(0.7978845608028654f*(x + 0.044715f*x3)));
}

// ---------------- MFMA GEMM, B pre-transposed bf16 [N][K] (unchanged from R5)
template<int EPI, typename TC>
__global__ __launch_bounds__(256) void gemm_bt(const bf16* __restrict__ A, int lda,
                                               const bf16* __restrict__ B, int ldb,
                                               const float* __restrict__ bias,
                                               TC* __restrict__ C, int ldc, int K){
    __shared__ bf16 As[128*64];
    __shared__ bf16 Bs[64*64];
    const int tid = threadIdx.x;
    const int w = tid >> 6, l = tid & 63;
    const int quad = l >> 4, lr = l & 15;
    const int wm = w & 1, wn = w >> 1;
    const int rowT = blockIdx.y * 128;
    const int colT = blockIdx.x * 64;

    f32x4 acc[4][2];
    #pragma unroll
    for (int i = 0; i < 4; ++i)
        #pragma unroll
        for (int j = 0; j < 2; ++j) acc[i][j] = (f32x4){0.f,0.f,0.f,0.f};

    for (int k0 = 0; k0 < K; k0 += 64){
        #pragma unroll
        for (int i = 0; i < 4; ++i){
            int g = i*256 + tid, r = g >> 3, c = g & 7;
            uint4 val = *(const uint4*)(A + (size_t)(rowT + r)*lda + k0 + c*8);
            *(uint4*)(As + r*64 + ((c ^ (r & 7))*8)) = val;
        }
        #pragma unroll
        for (int i = 0; i < 2; ++i){
            int g = i*256 + tid, r = g >> 3, c = g & 7;
            uint4 val = *(const uint4*)(B + (size_t)(colT + r)*ldb + k0 + c*8);
            *(uint4*)(Bs + r*64 + ((c ^ (r & 7))*8)) = val;
        }
        __syncthreads();
        #pragma unroll
        for (int kh = 0; kh < 2; ++kh){
            bf16x8 af[4], bfr[2];
            #pragma unroll
            for (int i = 0; i < 4; ++i){
                int r = wm*64 + i*16 + lr;
                af[i] = *(const bf16x8*)(As + r*64 + (((kh*4 + quad) ^ (r & 7))*8));
            }
            #pragma unroll
            for (int j = 0; j < 2; ++j){
                int r = wn*32 + j*16 + lr;
                bfr[j] = *(const bf16x8*)(Bs + r*64 + (((kh*4 + quad) ^ (r & 7))*8));
            }
            #pragma unroll
            for (int i = 0; i < 4; ++i)
                #pragma unroll
                for (int j = 0; j < 2; ++j)
                    acc[i][j] = __builtin_amdgcn_mfma_f32_16x16x32_bf16(af[i], bfr[j], acc[i][j], 0, 0, 0);
        }
        __syncthreads();
    }

    #pragma unroll
    for (int i = 0; i < 4; ++i){
        #pragma unroll
        for (int j = 0; j < 2; ++j){
            const int row = rowT + wm*64 + i*16 + quad*4;
            const int col = colT + wn*32 + j*16 + lr;
            const float bb = bias ? bias[col] : 0.f;
            #pragma unroll
            for (int r = 0; r < 4; ++r){
                float val = acc[i][j][r] + bb;
                TC* cp = C + (size_t)(row + r)*ldc + col;
                if (EPI == 2) val = gelu_tanh(val);
                if (EPI == 1) val += *(float*)cp;
                if (EPI == 0 || EPI == 2) *(bf16*)cp = __float2bfloat16(val);
                else                      *(float*)cp = val;
            }
        }
    }
}

// ---------------- LayerNorm: wave per token, shuffle reductions
__global__ __launch_bounds__(256) void ln_wave(const float* __restrict__ x,
                                               const float* __restrict__ sc,
                                               const float* __restrict__ bs,
                                               bf16* __restrict__ y){
    const int tid = threadIdx.x, w = tid >> 6, l = tid & 63;
    const int t = blockIdx.x*4 + w;
    const float4* xr = (const float4*)(x + (size_t)t*CW);
    float4 a[3];
    #pragma unroll
    for (int i = 0; i < 3; ++i) a[i] = xr[l + 64*i];
    float s = 0.f;
    #pragma unroll
    for (int i = 0; i < 3; ++i) s += a[i].x + a[i].y + a[i].z + a[i].w;
    #pragma unroll
    for (int off = 1; off < 64; off <<= 1) s += __shfl_xor(s, off);
    const float m = s * (1.0f/768.0f);
    float vs = 0.f;
    #pragma unroll
    for (int i = 0; i < 3; ++i){
        float dx = a[i].x-m, dy = a[i].y-m, dz = a[i].z-m, dw = a[i].w-m;
        vs += dx*dx + dy*dy + dz*dz + dw*dw;
    }
    #pragma unroll
    for (int off = 1; off < 64; off <<= 1) vs += __shfl_xor(vs, off);
    const float rs = rsqrtf(vs*(1.0f/768.0f) + 1e-6f);
    const float4* scp = (const float4*)sc;
    const float4* bsp = (const float4*)bs;
    uint2* yr = (uint2*)(y + (size_t)t*CW);
    #pragma unroll
    for (int i = 0; i < 3; ++i){
        float4 sv = scp[l + 64*i], bv = bsp[l + 64*i];
        float r0 = (a[i].x-m)*rs*sv.x + bv.x;
        float r1 = (a[i].y-m)*rs*sv.y + bv.y;
        float r2 = (a[i].z-m)*rs*sv.z + bv.z;
        float r3 = (a[i].w-m)*rs*sv.w + bv.w;
        yr[l + 64*i] = make_uint2(bfpair(r0,r1), bfpair(r2,r3));
    }
}

// ---------------- RoPE apply on bf16 (in place)
__global__ void rope_apply(bf16* __restrict__ t, const float* __restrict__ rc){
    int idx = blockIdx.x*256 + threadIdx.x;
    int tok = idx / 384;
    int r = idx % 384;
    int hh = r >> 5, p = r & 31;
    int l = tok % LTOK;
    float c, s;
    if (p < 16){ c = rc[l*16 + p];            s = rc[9216 + l*16 + p]; }
    else       { c = rc[18432 + l*16 + p-16]; s = rc[27648 + l*16 + p-16]; }
    bf16* pp = t + (size_t)tok*CW + hh*64 + 2*p;
    unsigned u = *(unsigned*)pp;
    bf16 lo = *(bf16*)&u; unsigned short hi16 = u >> 16; bf16 hi = *(bf16*)&hi16;
    float x = b2f(lo), y = b2f(hi);
    *(unsigned*)pp = bfpair(x*c - y*s, x*s + y*c);
}

// ---------------- V transpose: v [tok][CW] bf16 -> vT [(n,h)][d=64][576]
__global__ __launch_bounds__(256) void vtrans(const bf16* __restrict__ v, bf16* __restrict__ vT){
    __shared__ bf16 tile[64][72];
    const int t0 = blockIdx.x*64, hI = blockIdx.y, nI = blockIdx.z;
    const size_t base = ((size_t)nI*LTOK + t0)*CW + hI*64;
    const int tid = threadIdx.x;
    #pragma unroll
    for (int i = 0; i < 2; ++i){
        int g = i*256 + tid, r = g >> 3, c = g & 7;
        *(uint4*)&tile[r][c*8] = *(const uint4*)(v + base + (size_t)r*CW + c*8);
    }
    __syncthreads();
    const size_t obase = ((size_t)(nI*NH + hI)*64)*576 + t0;
    #pragma unroll
    for (int i = 0; i < 2; ++i){
        int g = i*256 + tid, d = g >> 3, c = g & 7;
        bf16 tmp[8];
        #pragma unroll
        for (int j = 0; j < 8; ++j) tmp[j] = tile[c*8 + j][d];
        *(uint4*)(vT + obase + (size_t)d*576 + c*8) = *(uint4*)tmp;
    }
}

// ---------------- Flash attention: block = 64 q rows x (head,batch)
// wave w handles q rows q0+w*16..+15. Online softmax in registers.
__global__ __launch_bounds__(256) void attn_flash(const bf16* __restrict__ q,
                                                  const bf16* __restrict__ k,
                                                  const bf16* __restrict__ vT,
                                                  bf16* __restrict__ o){
    __shared__ bf16 Ks[64*72];      // K chunk [key][d]
    __shared__ bf16 Vs[64*72];      // V chunk [d][key] (from vT)
    __shared__ bf16 Ps[64*72];      // P [q][key]
    __shared__ float alph[64];
    __shared__ float lsum[64];
    const int tid = threadIdx.x;
    const int w = tid >> 6, l = tid & 63;
    const int quad = l >> 4, lr = l & 15;
    const int q0 = blockIdx.x * 64;
    const int hI = blockIdx.y, nI = blockIdx.z;
    const size_t tokBase = (size_t)nI * LTOK;
    const int off = hI * 64;
    const size_t vbase = ((size_t)(nI*NH + hI)*64)*576;

    // Q fragments (A-layout), loaded once from global: lane lr -> q row w*16+lr
    bf16x8 qf[2];
    #pragma unroll
    for (int kh = 0; kh < 2; ++kh)
        qf[kh] = *(const bf16x8*)(q + (tokBase + q0 + w*16 + lr)*CW + off + kh*32 + quad*8);

    f32x4 oacc[4];
    #pragma unroll
    for (int j = 0; j < 4; ++j) oacc[j] = (f32x4){0.f,0.f,0.f,0.f};
    float m_run = -3.0e38f, l_run = 0.f;

    for (int ch = 0; ch < 9; ++ch){
        __syncthreads();                      // previous chunk's reads complete
        #pragma unroll
        for (int i = 0; i < 2; ++i){          // stage K [key][d]
            int g = i*256 + tid, r = g >> 3, c = g & 7;
            *(uint4*)(Ks + r*72 + c*8) = *(const uint4*)(k + (tokBase + ch*64 + r)*CW + off + c*8);
        }
        #pragma unroll
        for (int i = 0; i < 2; ++i){          // stage V [d][key]
            int g = i*256 + tid, d = g >> 3, c = g & 7;
            *(uint4*)(Vs + d*72 + c*8) = *(const uint4*)(vT + vbase + (size_t)d*576 + ch*64 + c*8);
        }
        __syncthreads();

        // S^T tiles: C[row=key=t*16+quad*4+r][col=q=lr]
        f32x4 st[4];
        #pragma unroll
        for (int t = 0; t < 4; ++t){
            st[t] = (f32x4){0.f,0.f,0.f,0.f};
            #pragma unroll
            for (int kh = 0; kh < 2; ++kh){
                bf16x8 kf = *(const bf16x8*)(Ks + (t*16 + lr)*72 + kh*32 + quad*8);
                st[t] = __builtin_amdgcn_mfma_f32_16x16x32_bf16(kf, qf[kh], st[t], 0, 0, 0);
            }
        }
        // online softmax (per q column = per lane lr, across quads)
        float lm = -3.0e38f;
        #pragma unroll
        for (int t = 0; t < 4; ++t)
            #pragma unroll
            for (int r = 0; r < 4; ++r){
                st[t][r] *= 0.125f;
                lm = fmaxf(lm, st[t][r]);
            }
        lm = fmaxf(lm, __shfl_xor(lm, 16));
        lm = fmaxf(lm, __shfl_xor(lm, 32));
        float mn = fmaxf(m_run, lm);
        float alpha = __expf(m_run - mn);
        m_run = mn;
        float ls = 0.f;
        #pragma unroll
        for (int t = 0; t < 4; ++t)
            #pragma unroll
            for (int r = 0; r < 4; ++r){
                float p = __expf(st[t][r] - mn);
                st[t][r] = p; ls += p;
            }
        ls += __shfl_xor(ls, 16);
        ls += __shfl_xor(ls, 32);
        l_run = l_run*alpha + ls;
        if ((tid & 48) == 0) alph[w*16 + lr] = alpha;
        // P -> LDS [q][key]
        #pragma unroll
        for (int t = 0; t < 4; ++t)
            #pragma unroll
            for (int r = 0; r < 4; ++r)
                Ps[(w*16 + lr)*72 + t*16 + quad*4 + r] = __float2bfloat16(st[t][r]);
        // rescale O by alpha (per q row = quad*4+r)
        float af[4];
        #pragma unroll
        for (int r = 0; r < 4; ++r) af[r] = alph[w*16 + quad*4 + r];
        #pragma unroll
        for (int j = 0; j < 4; ++j)
            #pragma unroll
            for (int r = 0; r < 4; ++r) oacc[j][r] *= af[r];
        // PV: O[q][d] += P[q][k] V[k][d]
        #pragma unroll
        for (int kh = 0; kh < 2; ++kh){
            bf16x8 pf = *(const bf16x8*)(Ps + (w*16 + lr)*72 + kh*32 + quad*8);
            #pragma unroll
            for (int j = 0; j < 4; ++j){
                bf16x8 vf = *(const bf16x8*)(Vs + (j*16 + lr)*72 + kh*32 + quad*8);
                oacc[j] = __builtin_amdgcn_mfma_f32_16x16x32_bf16(pf, vf, oacc[j], 0, 0, 0);
            }
        }
    }

    if ((tid & 48) == 0) lsum[w*16 + lr] = l_run;
    float linv[4];
    #pragma unroll
    for (int r = 0; r < 4; ++r) linv[r] = 1.0f / lsum[w*16 + quad*4 + r];
    #pragma unroll
    for (int j = 0; j < 4; ++j)
        #pragma unroll
        for (int r = 0; r < 4; ++r)
            o[(tokBase + q0 + w*16 + quad*4 + r)*CW + off + j*16 + lr] =
                __float2bfloat16(oacc[j][r] * linv[r]);
}

// ---------------- final mean over tokens (bf16 y) -> f32 out (8,768)
__global__ void mean_kernel(const bf16* __restrict__ y, float* __restrict__ out){
    int c = blockIdx.x*256 + threadIdx.x;
    int n = blockIdx.y;
    float s = 0.f;
    for (int l = 0; l < LTOK; ++l) s += b2f(y[((size_t)n*LTOK + l)*CW + c]);
    out[n*CW + c] = s * (1.0f/576.0f);
}

extern "C" void kernel_launch(void* const* d_in, const int* in_sizes, int n_in,
                              void* d_out, int out_size, void* d_ws, size_t ws_size,
                              hipStream_t stream){
    const float* image = (const float*)d_in[0];
    const float* convk = (const float*)d_in[1];
    const float* convb = (const float*)d_in[2];
    const float* ln1s  = (const float*)d_in[3];
    const float* ln1b  = (const float*)d_in[4];
    const float* wq    = (const float*)d_in[5];
    const float* bq    = (const float*)d_in[6];
    const float* wk    = (const float*)d_in[7];
    const float* bk    = (const float*)d_in[8];
    const float* wv    = (const float*)d_in[9];
    const float* bv    = (const float*)d_in[10];
    const float* wo    = (const float*)d_in[11];
    const float* bo    = (const float*)d_in[12];
    const float* ln2s  = (const float*)d_in[13];
    const float* ln2b  = (const float*)d_in[14];
    const float* w1    = (const float*)d_in[15];
    const float* b1    = (const float*)d_in[16];
    const float* w2    = (const float*)d_in[17];
    const float* b2    = (const float*)d_in[18];
    const float* lnfs  = (const float*)d_in[19];
    const float* lnfb  = (const float*)d_in[20];
    float* out = (float*)d_out;

    const size_t u = (size_t)NT*CW;
    float* ws    = (float*)d_ws;
    float* ropeC = ws;
    float* x     = ws + 36864;
    bf16*  y     = (bf16*)(x + u);
    bf16*  q     = y + u;
    bf16*  k     = q + u;
    bf16*  v     = k + u;
    bf16*  vT    = v + u;
    bf16*  wring = vT + u;
    bf16*  o     = y;
    bf16*  h     = q;

    bf16* wqT = wring;
    bf16* wkT = wqT + 589824;
    bf16* wvT = wkT + 589824;
    bf16* woT = wvT + 589824;
    bf16* w1T = woT + 589824;
    bf16* w2T = w1T + 2359296;

    rope_cache_kernel<<<36, 256, 0, stream>>>(ropeC);
    patch_gather<<<(NT*CW)/256, 256, 0, stream>>>(image, y);
    wtrans<<<dim3(24,24), 256, 0, stream>>>(convk, wqT, CW, CW);
    gemm_bt<3,float><<<dim3(12,36), 256, 0, stream>>>(y, CW, wqT, CW, convb, x, CW, CW);

    for (int l = 0; l < DEPTH; ++l){
        wtrans<<<dim3(24,24), 256, 0, stream>>>(wq + (size_t)l*CW*CW, wqT, CW, CW);
        wtrans<<<dim3(24,24), 256, 0, stream>>>(wk + (size_t)l*CW*CW, wkT, CW, CW);
        wtrans<<<dim3(24,24), 256, 0, stream>>>(wv + (size_t)l*CW*CW, wvT, CW, CW);
        wtrans<<<dim3(24,24), 256, 0, stream>>>(wo + (size_t)l*CW*CW, woT, CW, CW);
        wtrans<<<dim3(96,24), 256, 0, stream>>>(w1 + (size_t)l*CW*MLPW, w1T, CW, MLPW);
        wtrans<<<dim3(24,96), 256, 0, stream>>>(w2 + (size_t)l*MLPW*CW, w2T, MLPW, CW);

        ln_wave<<<NT/4, 256, 0, stream>>>(x, ln1s + l*CW, ln1b + l*CW, y);
        gemm_bt<0,bf16><<<dim3(12,36), 256, 0, stream>>>(y, CW, wqT, CW, bq + l*CW, q, CW, CW);
        gemm_bt<0,bf16><<<dim3(12,36), 256, 0, stream>>>(y, CW, wkT, CW, bk + l*CW, k, CW, CW);
        gemm_bt<0,bf16><<<dim3(12,36), 256, 0, stream>>>(y, CW, wvT, CW, bv + l*CW, v, CW, CW);
        rope_apply<<<(NT*384)/256, 256, 0, stream>>>(q, ropeC);
        rope_apply<<<(NT*384)/256, 256, 0, stream>>>(k, ropeC);
        vtrans<<<dim3(9, NH, NBATCH), 256, 0, stream>>>(v, vT);
        attn_flash<<<dim3(9, NH, NBATCH), 256, 0, stream>>>(q, k, vT, o);
        gemm_bt<1,float><<<dim3(12,36), 256, 0, stream>>>(o, CW, woT, CW, bo + l*CW, x, CW, CW);
        ln_wave<<<NT/4, 256, 0, stream>>>(x, ln2s + l*CW, ln2b + l*CW, y);
        for (int hf = 0; hf < 2; ++hf){
            gemm_bt<2,bf16><<<dim3(24,36), 256, 0, stream>>>(y, CW,
                w1T + (size_t)hf*1536*CW, CW, b1 + l*MLPW + hf*1536, h, 1536, CW);
            gemm_bt<1,float><<<dim3(12,36), 256, 0, stream>>>(h, 1536,
                w2T + hf*1536, MLPW,
                (hf == 0) ? (b2 + l*CW) : (const float*)nullptr, x, CW, 1536);
        }
    }
    ln_wave<<<NT/4, 256, 0, stream>>>(x, lnfs, lnfb, y);
    mean_kernel<<<dim3(3, NBATCH), 256, 0, stream>>>(y, out);
}

// Round 7
// 1242.242 us; speedup vs baseline: 6.1159x; 1.0510x over previous
//
#include <hip/hip_runtime.h>
#include <hip/hip_bf16.h>

typedef __hip_bfloat16 bf16;
typedef __bf16 bf16x8 __attribute__((ext_vector_type(8)));
typedef float f32x4  __attribute__((ext_vector_type(4)));

#define NBATCH 8
#define LTOK   576
#define NT     4608
#define CW     768
#define NH     12
#define HDIM   64
#define DEPTH  4
#define MLPW   3072
#define GRIDP  24
#define IMGS   384
#define QKVW   2304

static __device__ __forceinline__ unsigned bfpair(float a, float b){
    bf16 x = __float2bfloat16(a), y = __float2bfloat16(b);
    return ((unsigned)*(unsigned short*)&y << 16) | *(unsigned short*)&x;
}
static __device__ __forceinline__ float b2f(bf16 v){ return __bfloat162float(v); }

// ---------------- RoPE cache ----------------
__global__ void rope_cache_kernel(float* __restrict__ rc){
    int idx = blockIdx.x*256 + threadIdx.x;
    if (idx >= LTOK*16) return;
    int l = idx >> 4, f = idx & 15;
    int py = l / GRIDP, px = l % GRIDP;
    float u = (px + 0.5f) / (float)GRIDP;
    float v = (py + 0.5f) / (float)GRIDP;
    float fr = (float)f / (15.0f + 1e-9f);
    float inv = expf(-fr * 9.210340371976184f);
    float sx, cx, sy, cy;
    sincosf(u * inv, &sx, &cx);
    sincosf(v * inv, &sy, &cy);
    rc[idx]         = cx;
    rc[idx + 9216]  = sx;
    rc[idx + 18432] = cy;
    rc[idx + 27648] = sy;
}

// ---------------- patch gather: f32 image -> bf16 patches (4608,768)
__global__ void patch_gather(const float* __restrict__ img, bf16* __restrict__ p){
    int idx = blockIdx.x*256 + threadIdx.x;
    int t = idx / CW, kk = idx % CW;
    int n = t / LTOK, l = t % LTOK;
    int py = l / GRIDP, px = l % GRIDP;
    int i = kk / 48, r = kk % 48, j = r / 3, c = r % 3;
    p[idx] = __float2bfloat16(img[((size_t)(n*IMGS + py*16 + i)*IMGS + px*16 + j)*3 + c]);
}

// ---------------- batched weight transpose+convert: f32 [K][N] -> bf16 [N][K]
__global__ __launch_bounds__(256) void wtrans_b(const float* __restrict__ in, bf16* __restrict__ out,
                                                int K, int N, size_t inStride, size_t outStride){
    in  += blockIdx.z * inStride;
    out += blockIdx.z * outStride;
    __shared__ float t[32][33];
    const int n0 = blockIdx.x*32, k0 = blockIdx.y*32;
    const int tx = threadIdx.x & 31, ty = threadIdx.x >> 5;
    #pragma unroll
    for (int r = 0; r < 4; ++r)
        t[ty + 8*r][tx] = in[(size_t)(k0 + ty + 8*r)*N + n0 + tx];
    __syncthreads();
    #pragma unroll
    for (int r = 0; r < 4; ++r)
        out[(size_t)(n0 + ty + 8*r)*K + k0 + tx] = __float2bfloat16(t[tx][ty + 8*r]);
}

// ---------------- pack qkv biases: [4][2304] from bq,bk,bv
__global__ void bias_pack(const float* __restrict__ bq, const float* __restrict__ bk,
                          const float* __restrict__ bv, float* __restrict__ o){
    int idx = blockIdx.x*256 + threadIdx.x;    // 4*2304
    int l = idx / QKVW, r = idx % QKVW;
    const float* src = (r < 768) ? (bq + l*768 + r) :
                       (r < 1536) ? (bk + l*768 + r - 768) : (bv + l*768 + r - 1536);
    o[idx] = *src;
}

static __device__ __forceinline__ float gelu_tanh(float x){
    float x3 = x*x*x;
    return 0.5f*x*(1.0f + tanhf(0.7978845608028654f*(x + 0.044715f*x3)));
}

// ---------------- MFMA GEMM 128x128, BK=64, B pre-transposed bf16 [N][K]
// wave w: rows (w&1)*64, cols (w>>1)*64. 32 MFMA : 16 ds_read_b128 per K-step.
// EPI: 0 = bf16 store, 1 = fp32 residual add, 2 = bf16 gelu, 3 = fp32 store
template<int EPI, typename TC>
__global__ __launch_bounds__(256) void gemm128(const bf16* __restrict__ A, int lda,
                                               const bf16* __restrict__ B, int ldb,
                                               const float* __restrict__ bias,
                                               TC* __restrict__ C, int ldc, int K){
    __shared__ bf16 As[128*64];   // row r at r*64; 8-elem chunk c stored at (c^(r&7))
    __shared__ bf16 Bs[128*64];
    const int tid = threadIdx.x;
    const int w = tid >> 6, l = tid & 63;
    const int quad = l >> 4, lr = l & 15;
    const int wm = w & 1, wn = w >> 1;
    const int rowT = blockIdx.y * 128;
    const int colT = blockIdx.x * 128;

    f32x4 acc[4][4];
    #pragma unroll
    for (int i = 0; i < 4; ++i)
        #pragma unroll
        for (int j = 0; j < 4; ++j) acc[i][j] = (f32x4){0.f,0.f,0.f,0.f};

    for (int k0 = 0; k0 < K; k0 += 64){
        #pragma unroll
        for (int i = 0; i < 4; ++i){
            int g = i*256 + tid, r = g >> 3, c = g & 7;
            uint4 val = *(const uint4*)(A + (size_t)(rowT + r)*lda + k0 + c*8);
            *(uint4*)(As + r*64 + ((c ^ (r & 7))*8)) = val;
        }
        #pragma unroll
        for (int i = 0; i < 4; ++i){
            int g = i*256 + tid, r = g >> 3, c = g & 7;
            uint4 val = *(const uint4*)(B + (size_t)(colT + r)*ldb + k0 + c*8);
            *(uint4*)(Bs + r*64 + ((c ^ (r & 7))*8)) = val;
        }
        __syncthreads();
        #pragma unroll
        for (int kh = 0; kh < 2; ++kh){
            bf16x8 af[4], bfr[4];
            #pragma unroll
            for (int i = 0; i < 4; ++i){
                int r = wm*64 + i*16 + lr;
                af[i] = *(const bf16x8*)(As + r*64 + (((kh*4 + quad) ^ (r & 7))*8));
            }
            #pragma unroll
            for (int j = 0; j < 4; ++j){
                int r = wn*64 + j*16 + lr;
                bfr[j] = *(const bf16x8*)(Bs + r*64 + (((kh*4 + quad) ^ (r & 7))*8));
            }
            #pragma unroll
            for (int i = 0; i < 4; ++i)
                #pragma unroll
                for (int j = 0; j < 4; ++j)
                    acc[i][j] = __builtin_amdgcn_mfma_f32_16x16x32_bf16(af[i], bfr[j], acc[i][j], 0, 0, 0);
        }
        __syncthreads();
    }

    #pragma unroll
    for (int i = 0; i < 4; ++i){
        #pragma unroll
        for (int j = 0; j < 4; ++j){
            const int row = rowT + wm*64 + i*16 + quad*4;
            const int col = colT + wn*64 + j*16 + lr;
            const float bb = bias ? bias[col] : 0.f;
            #pragma unroll
            for (int r = 0; r < 4; ++r){
                float val = acc[i][j][r] + bb;
                TC* cp = C + (size_t)(row + r)*ldc + col;
                if (EPI == 2) val = gelu_tanh(val);
                if (EPI == 1) val += *(float*)cp;
                if (EPI == 0 || EPI == 2) *(bf16*)cp = __float2bfloat16(val);
                else                      *(float*)cp = val;
            }
        }
    }
}

// ---------------- LayerNorm: wave per token, shuffle reductions
__global__ __launch_bounds__(256) void ln_wave(const float* __restrict__ x,
                                               const float* __restrict__ sc,
                                               const float* __restrict__ bs,
                                               bf16* __restrict__ y){
    const int tid = threadIdx.x, w = tid >> 6, l = tid & 63;
    const int t = blockIdx.x*4 + w;
    const float4* xr = (const float4*)(x + (size_t)t*CW);
    float4 a[3];
    #pragma unroll
    for (int i = 0; i < 3; ++i) a[i] = xr[l + 64*i];
    float s = 0.f;
    #pragma unroll
    for (int i = 0; i < 3; ++i) s += a[i].x + a[i].y + a[i].z + a[i].w;
    #pragma unroll
    for (int off = 1; off < 64; off <<= 1) s += __shfl_xor(s, off);
    const float m = s * (1.0f/768.0f);
    float vs = 0.f;
    #pragma unroll
    for (int i = 0; i < 3; ++i){
        float dx = a[i].x-m, dy = a[i].y-m, dz = a[i].z-m, dw = a[i].w-m;
        vs += dx*dx + dy*dy + dz*dz + dw*dw;
    }
    #pragma unroll
    for (int off = 1; off < 64; off <<= 1) vs += __shfl_xor(vs, off);
    const float rs = rsqrtf(vs*(1.0f/768.0f) + 1e-6f);
    const float4* scp = (const float4*)sc;
    const float4* bsp = (const float4*)bs;
    uint2* yr = (uint2*)(y + (size_t)t*CW);
    #pragma unroll
    for (int i = 0; i < 3; ++i){
        float4 sv = scp[l + 64*i], bv = bsp[l + 64*i];
        float r0 = (a[i].x-m)*rs*sv.x + bv.x;
        float r1 = (a[i].y-m)*rs*sv.y + bv.y;
        float r2 = (a[i].z-m)*rs*sv.z + bv.z;
        float r3 = (a[i].w-m)*rs*sv.w + bv.w;
        yr[l + 64*i] = make_uint2(bfpair(r0,r1), bfpair(r2,r3));
    }
}

// ---------------- RoPE apply on q and k inside packed qkv (in place)
__global__ void rope_qk(bf16* __restrict__ qkv, const float* __restrict__ rc){
    int idx = blockIdx.x*256 + threadIdx.x;   // NT*768 pairs (q:384, k:384 per token)
    int tok = idx / 768;
    int r = idx % 768;
    int part = r >> 9;                         // 0: q (r<512)? no — split at 384
    int rr = r;
    int base;
    if (r < 384){ base = 0; rr = r; } else { base = 768; rr = r - 384; }
    int hh = rr >> 5, p = rr & 31;
    int l = tok % LTOK;
    float c, s;
    if (p < 16){ c = rc[l*16 + p];            s = rc[9216 + l*16 + p]; }
    else       { c = rc[18432 + l*16 + p-16]; s = rc[27648 + l*16 + p-16]; }
    bf16* pp = qkv + (size_t)tok*QKVW + base + hh*64 + 2*p;
    unsigned u = *(unsigned*)pp;
    bf16 lo = *(bf16*)&u; unsigned short hi16 = u >> 16; bf16 hi = *(bf16*)&hi16;
    float x = b2f(lo), y = b2f(hi);
    *(unsigned*)pp = bfpair(x*c - y*s, x*s + y*c);
    (void)part;
}

// ---------------- V transpose: qkv v-part -> vT [(n,h)][d=64][576]
__global__ __launch_bounds__(256) void vtrans(const bf16* __restrict__ qkv, bf16* __restrict__ vT){
    __shared__ bf16 tile[64][72];
    const int t0 = blockIdx.x*64, hI = blockIdx.y, nI = blockIdx.z;
    const size_t base = ((size_t)nI*LTOK + t0)*QKVW + 1536 + hI*64;
    const int tid = threadIdx.x;
    #pragma unroll
    for (int i = 0; i < 2; ++i){
        int g = i*256 + tid, r = g >> 3, c = g & 7;
        *(uint4*)&tile[r][c*8] = *(const uint4*)(qkv + base + (size_t)r*QKVW + c*8);
    }
    __syncthreads();
    const size_t obase = ((size_t)(nI*NH + hI)*64)*576 + t0;
    #pragma unroll
    for (int i = 0; i < 2; ++i){
        int g = i*256 + tid, d = g >> 3, c = g & 7;
        bf16 tmp[8];
        #pragma unroll
        for (int j = 0; j < 8; ++j) tmp[j] = tile[c*8 + j][d];
        *(uint4*)(vT + obase + (size_t)d*576 + c*8) = *(uint4*)tmp;
    }
}

// ---------------- Flash attention: block = 64 q rows x (head,batch)
__global__ __launch_bounds__(256) void attn_flash(const bf16* __restrict__ qkv,
                                                  const bf16* __restrict__ vT,
                                                  bf16* __restrict__ o){
    __shared__ bf16 Ks[64*72];
    __shared__ bf16 Vs[64*72];
    __shared__ bf16 Ps[64*72];
    __shared__ float alph[64];
    __shared__ float lsum[64];
    const int tid = threadIdx.x;
    const int w = tid >> 6, l = tid & 63;
    const int quad = l >> 4, lr = l & 15;
    const int q0 = blockIdx.x * 64;
    const int hI = blockIdx.y, nI = blockIdx.z;
    const size_t tokBase = (size_t)nI * LTOK;
    const int off = hI * 64;
    const size_t vbase = ((size_t)(nI*NH + hI)*64)*576;

    bf16x8 qf[2];
    #pragma unroll
    for (int kh = 0; kh < 2; ++kh)
        qf[kh] = *(const bf16x8*)(qkv + (tokBase + q0 + w*16 + lr)*QKVW + off + kh*32 + quad*8);

    f32x4 oacc[4];
    #pragma unroll
    for (int j = 0; j < 4; ++j) oacc[j] = (f32x4){0.f,0.f,0.f,0.f};
    float m_run = -3.0e38f, l_run = 0.f;

    for (int ch = 0; ch < 9; ++ch){
        __syncthreads();
        #pragma unroll
        for (int i = 0; i < 2; ++i){
            int g = i*256 + tid, r = g >> 3, c = g & 7;
            *(uint4*)(Ks + r*72 + c*8) =
                *(const uint4*)(qkv + (tokBase + ch*64 + r)*QKVW + 768 + off + c*8);
        }
        #pragma unroll
        for (int i = 0; i < 2; ++i){
            int g = i*256 + tid, d = g >> 3, c = g & 7;
            *(uint4*)(Vs + d*72 + c*8) = *(const uint4*)(vT + vbase + (size_t)d*576 + ch*64 + c*8);
        }
        __syncthreads();

        f32x4 st[4];
        #pragma unroll
        for (int t = 0; t < 4; ++t){
            st[t] = (f32x4){0.f,0.f,0.f,0.f};
            #pragma unroll
            for (int kh = 0; kh < 2; ++kh){
                bf16x8 kf = *(const bf16x8*)(Ks + (t*16 + lr)*72 + kh*32 + quad*8);
                st[t] = __builtin_amdgcn_mfma_f32_16x16x32_bf16(kf, qf[kh], st[t], 0, 0, 0);
            }
        }
        float lm = -3.0e38f;
        #pragma unroll
        for (int t = 0; t < 4; ++t)
            #pragma unroll
            for (int r = 0; r < 4; ++r){
                st[t][r] *= 0.125f;
                lm = fmaxf(lm, st[t][r]);
            }
        lm = fmaxf(lm, __shfl_xor(lm, 16));
        lm = fmaxf(lm, __shfl_xor(lm, 32));
        float mn = fmaxf(m_run, lm);
        float alpha = __expf(m_run - mn);
        m_run = mn;
        float ls = 0.f;
        #pragma unroll
        for (int t = 0; t < 4; ++t)
            #pragma unroll
            for (int r = 0; r < 4; ++r){
                float p = __expf(st[t][r] - mn);
                st[t][r] = p; ls += p;
            }
        ls += __shfl_xor(ls, 16);
        ls += __shfl_xor(ls, 32);
        l_run = l_run*alpha + ls;
        if ((tid & 48) == 0) alph[w*16 + lr] = alpha;
        #pragma unroll
        for (int t = 0; t < 4; ++t)
            #pragma unroll
            for (int r = 0; r < 4; ++r)
                Ps[(w*16 + lr)*72 + t*16 + quad*4 + r] = __float2bfloat16(st[t][r]);
        float af[4];
        #pragma unroll
        for (int r = 0; r < 4; ++r) af[r] = alph[w*16 + quad*4 + r];
        #pragma unroll
        for (int j = 0; j < 4; ++j)
            #pragma unroll
            for (int r = 0; r < 4; ++r) oacc[j][r] *= af[r];
        #pragma unroll
        for (int kh = 0; kh < 2; ++kh){
            bf16x8 pf = *(const bf16x8*)(Ps + (w*16 + lr)*72 + kh*32 + quad*8);
            #pragma unroll
            for (int j = 0; j < 4; ++j){
                bf16x8 vf = *(const bf16x8*)(Vs + (j*16 + lr)*72 + kh*32 + quad*8);
                oacc[j] = __builtin_amdgcn_mfma_f32_16x16x32_bf16(pf, vf, oacc[j], 0, 0, 0);
            }
        }
    }

    if ((tid & 48) == 0) lsum[w*16 + lr] = l_run;
    float linv[4];
    #pragma unroll
    for (int r = 0; r < 4; ++r) linv[r] = 1.0f / lsum[w*16 + quad*4 + r];
    #pragma unroll
    for (int j = 0; j < 4; ++j)
        #pragma unroll
        for (int r = 0; r < 4; ++r)
            o[(tokBase + q0 + w*16 + quad*4 + r)*CW + off + j*16 + lr] =
                __float2bfloat16(oacc[j][r] * linv[r]);
}

// ---------------- final mean over tokens (bf16 y) -> f32 out (8,768)
__global__ void mean_kernel(const bf16* __restrict__ y, float* __restrict__ out){
    int c = blockIdx.x*256 + threadIdx.x;
    int n = blockIdx.y;
    float s = 0.f;
    for (int l = 0; l < LTOK; ++l) s += b2f(y[((size_t)n*LTOK + l)*CW + c]);
    out[n*CW + c] = s * (1.0f/576.0f);
}

extern "C" void kernel_launch(void* const* d_in, const int* in_sizes, int n_in,
                              void* d_out, int out_size, void* d_ws, size_t ws_size,
                              hipStream_t stream){
    const float* image = (const float*)d_in[0];
    const float* convk = (const float*)d_in[1];
    const float* convb = (const float*)d_in[2];
    const float* ln1s  = (const float*)d_in[3];
    const float* ln1b  = (const float*)d_in[4];
    const float* wq    = (const float*)d_in[5];
    const float* bq    = (const float*)d_in[6];
    const float* wk    = (const float*)d_in[7];
    const float* bk    = (const float*)d_in[8];
    const float* wv    = (const float*)d_in[9];
    const float* bv    = (const float*)d_in[10];
    const float* wo    = (const float*)d_in[11];
    const float* bo    = (const float*)d_in[12];
    const float* ln2s  = (const float*)d_in[13];
    const float* ln2b  = (const float*)d_in[14];
    const float* w1    = (const float*)d_in[15];
    const float* b1    = (const float*)d_in[16];
    const float* w2    = (const float*)d_in[17];
    const float* b2    = (const float*)d_in[18];
    const float* lnfs  = (const float*)d_in[19];
    const float* lnfb  = (const float*)d_in[20];
    float* out = (float*)d_out;

    const size_t u = (size_t)NT*CW;          // 3538944
    float* ws    = (float*)d_ws;
    float* ropeC = ws;                        // 36864 f32
    float* bqkvA = ws + 36864;                // 4*2304 f32
    float* x     = bqkvA + 4*QKVW;            // fp32 residual (u)
    bf16*  y     = (bf16*)(x + u);            // u
    bf16*  qkv   = y + u;                     // NT*2304
    bf16*  o     = qkv + (size_t)NT*QKVW;     // u
    bf16*  h     = o + u;                     // NT*3072
    bf16*  vT    = h + (size_t)NT*MLPW;       // u
    bf16*  convT = vT + u;                    // 589824
    bf16*  wqkvT = convT + 589824;            // 4 * 2304*768
    bf16*  woT   = wqkvT + (size_t)4*QKVW*CW; // 4 * 589824
    bf16*  w1T   = woT + (size_t)4*CW*CW;     // 4 * 2359296
    bf16*  w2T   = w1T + (size_t)4*CW*MLPW;   // 4 * 2359296

    rope_cache_kernel<<<36, 256, 0, stream>>>(ropeC);
    patch_gather<<<(NT*CW)/256, 256, 0, stream>>>(image, y);
    bias_pack<<<36, 256, 0, stream>>>(bq, bk, bv, bqkvA);
    // weight prep (all layers, batched over z)
    wtrans_b<<<dim3(24,24,1), 256, 0, stream>>>(convk, convT, CW, CW, 0, 0);
    wtrans_b<<<dim3(24,24,4), 256, 0, stream>>>(wq, wqkvT,            CW, CW, (size_t)CW*CW, (size_t)QKVW*CW);
    wtrans_b<<<dim3(24,24,4), 256, 0, stream>>>(wk, wqkvT + 589824,   CW, CW, (size_t)CW*CW, (size_t)QKVW*CW);
    wtrans_b<<<dim3(24,24,4), 256, 0, stream>>>(wv, wqkvT + 1179648,  CW, CW, (size_t)CW*CW, (size_t)QKVW*CW);
    wtrans_b<<<dim3(24,24,4), 256, 0, stream>>>(wo, woT,              CW, CW, (size_t)CW*CW, (size_t)CW*CW);
    wtrans_b<<<dim3(96,24,4), 256, 0, stream>>>(w1, w1T,  CW, MLPW, (size_t)CW*MLPW, (size_t)CW*MLPW);
    wtrans_b<<<dim3(24,96,4), 256, 0, stream>>>(w2, w2T, MLPW,  CW, (size_t)CW*MLPW, (size_t)CW*MLPW);

    gemm128<3,float><<<dim3(6,36), 256, 0, stream>>>(y, CW, convT, CW, convb, x, CW, CW);

    for (int l = 0; l < DEPTH; ++l){
        ln_wave<<<NT/4, 256, 0, stream>>>(x, ln1s + l*CW, ln1b + l*CW, y);
        gemm128<0,bf16><<<dim3(18,36), 256, 0, stream>>>(y, CW, wqkvT + (size_t)l*QKVW*CW, CW,
                                                         bqkvA + l*QKVW, qkv, QKVW, CW);
        rope_qk<<<(NT*768)/256, 256, 0, stream>>>(qkv, ropeC);
        vtrans<<<dim3(9, NH, NBATCH), 256, 0, stream>>>(qkv, vT);
        attn_flash<<<dim3(9, NH, NBATCH), 256, 0, stream>>>(qkv, vT, o);
        gemm128<1,float><<<dim3(6,36), 256, 0, stream>>>(o, CW, woT + (size_t)l*CW*CW, CW,
                                                         bo + l*CW, x, CW, CW);
        ln_wave<<<NT/4, 256, 0, stream>>>(x, ln2s + l*CW, ln2b + l*CW, y);
        gemm128<2,bf16><<<dim3(24,36), 256, 0, stream>>>(y, CW, w1T + (size_t)l*CW*MLPW, CW,
                                                         b1 + l*MLPW, h, MLPW, CW);
        gemm128<1,float><<<dim3(6,36), 256, 0, stream>>>(h, MLPW, w2T + (size_t)l*CW*MLPW, MLPW,
                                                         b2 + l*CW, x, CW, MLPW);
    }
    ln_wave<<<NT/4, 256, 0, stream>>>(x, lnfs, lnfb, y);
    mean_kernel<<<dim3(3, NBATCH), 256, 0, stream>>>(y, out);
}

// Round 8
// 1067.664 us; speedup vs baseline: 7.1159x; 1.1635x over previous
//
#include <hip/hip_runtime.h>
#include <hip/hip_bf16.h>

typedef __hip_bfloat16 bf16;
typedef __bf16 bf16x8 __attribute__((ext_vector_type(8)));
typedef float f32x4  __attribute__((ext_vector_type(4)));

#define NBATCH 8
#define LTOK   576
#define NT     4608
#define CW     768
#define NH     12
#define HDIM   64
#define DEPTH  4
#define MLPW   3072
#define GRIDP  24
#define IMGS   384
#define QKVW   2304

static __device__ __forceinline__ unsigned bfpair(float a, float b){
    bf16 x = __float2bfloat16(a), y = __float2bfloat16(b);
    return ((unsigned)*(unsigned short*)&y << 16) | *(unsigned short*)&x;
}
static __device__ __forceinline__ float b2f(bf16 v){ return __bfloat162float(v); }

// async global -> LDS, 16B per lane; LDS dest = wave-uniform base + lane*16
static __device__ __forceinline__ void gl_lds16(const bf16* g, bf16* l){
    __builtin_amdgcn_global_load_lds(
        (const __attribute__((address_space(1))) unsigned int*)(const void*)g,
        (__attribute__((address_space(3))) unsigned int*)(void*)l, 16, 0, 0);
}

// ---------------- RoPE cache ----------------
__global__ void rope_cache_kernel(float* __restrict__ rc){
    int idx = blockIdx.x*256 + threadIdx.x;
    if (idx >= LTOK*16) return;
    int l = idx >> 4, f = idx & 15;
    int py = l / GRIDP, px = l % GRIDP;
    float u = (px + 0.5f) / (float)GRIDP;
    float v = (py + 0.5f) / (float)GRIDP;
    float fr = (float)f / (15.0f + 1e-9f);
    float inv = expf(-fr * 9.210340371976184f);
    float sx, cx, sy, cy;
    sincosf(u * inv, &sx, &cx);
    sincosf(v * inv, &sy, &cy);
    rc[idx]         = cx;
    rc[idx + 9216]  = sx;
    rc[idx + 18432] = cy;
    rc[idx + 27648] = sy;
}

// ---------------- patch gather ----------------
__global__ void patch_gather(const float* __restrict__ img, bf16* __restrict__ p){
    int idx = blockIdx.x*256 + threadIdx.x;
    int t = idx / CW, kk = idx % CW;
    int n = t / LTOK, l = t % LTOK;
    int py = l / GRIDP, px = l % GRIDP;
    int i = kk / 48, r = kk % 48, j = r / 3, c = r % 3;
    p[idx] = __float2bfloat16(img[((size_t)(n*IMGS + py*16 + i)*IMGS + px*16 + j)*3 + c]);
}

// ---------------- batched weight transpose+convert: f32 [K][N] -> bf16 [N][K]
__global__ __launch_bounds__(256) void wtrans_b(const float* __restrict__ in, bf16* __restrict__ out,
                                                int K, int N, size_t inStride, size_t outStride){
    in  += blockIdx.z * inStride;
    out += blockIdx.z * outStride;
    __shared__ float t[32][33];
    const int n0 = blockIdx.x*32, k0 = blockIdx.y*32;
    const int tx = threadIdx.x & 31, ty = threadIdx.x >> 5;
    #pragma unroll
    for (int r = 0; r < 4; ++r)
        t[ty + 8*r][tx] = in[(size_t)(k0 + ty + 8*r)*N + n0 + tx];
    __syncthreads();
    #pragma unroll
    for (int r = 0; r < 4; ++r)
        out[(size_t)(n0 + ty + 8*r)*K + k0 + tx] = __float2bfloat16(t[tx][ty + 8*r]);
}

// ---------------- pack qkv biases ----------------
__global__ void bias_pack(const float* __restrict__ bq, const float* __restrict__ bk,
                          const float* __restrict__ bv, float* __restrict__ o){
    int idx = blockIdx.x*256 + threadIdx.x;    // 4*2304
    int l = idx / QKVW, r = idx % QKVW;
    const float* src = (r < 768) ? (bq + l*768 + r) :
                       (r < 1536) ? (bk + l*768 + r - 768) : (bv + l*768 + r - 1536);
    o[idx] = *src;
}

static __device__ __forceinline__ float gelu_tanh(float x){
    float x3 = x*x*x;
    return 0.5f*x*(1.0f + tanhf(0.7978845608028654f*(x + 0.044715f*x3)));
}

// ---------------- MFMA GEMM 128x64, BK=64, async LDS staging, B bf16 [N][K]
// LDS row pitch 64 bf16; chunk c of row r stored at position c^(r&7) (swizzle
// realized by permuting the GLOBAL source address; LDS dest is lane-contiguous).
// EPI: 0 = bf16 store, 1 = fp32 residual add, 2 = bf16 gelu, 3 = fp32 store
template<int EPI, typename TC>
__global__ __launch_bounds__(256) void gemm_a(const bf16* __restrict__ A, int lda,
                                              const bf16* __restrict__ B, int ldb,
                                              const float* __restrict__ bias,
                                              TC* __restrict__ C, int ldc, int K){
    __shared__ bf16 As[128*64];   // 16 KB
    __shared__ bf16 Bs[64*64];    //  8 KB
    const int tid = threadIdx.x;
    const int w = tid >> 6, l = tid & 63;
    const int quad = l >> 4, lr = l & 15;
    const int wm = w & 1, wn = w >> 1;
    const int rowT = blockIdx.y * 128;
    const int colT = blockIdx.x * 64;

    // per-lane source offsets for async staging
    const int srow = l >> 3;                       // 0..7 within segment
    const int schk = (l & 7) ^ (srow & 7);         // swizzled chunk
    f32x4 acc[4][2];
    #pragma unroll
    for (int i = 0; i < 4; ++i)
        #pragma unroll
        for (int j = 0; j < 2; ++j) acc[i][j] = (f32x4){0.f,0.f,0.f,0.f};

    for (int k0 = 0; k0 < K; k0 += 64){
        const bf16* Ab = A + (size_t)rowT*lda + k0;
        const bf16* Bb = B + (size_t)colT*ldb + k0;
        #pragma unroll
        for (int t = 0; t < 4; ++t){               // A: 16 segs of 8 rows, wave w -> w*4+t
            int s = w*4 + t;
            gl_lds16(Ab + (size_t)(s*8 + srow)*lda + schk*8, As + s*512);
        }
        #pragma unroll
        for (int t = 0; t < 2; ++t){               // B: 8 segs, wave w -> w*2+t
            int s = w*2 + t;
            gl_lds16(Bb + (size_t)(s*8 + srow)*ldb + schk*8, Bs + s*512);
        }
        __syncthreads();
        #pragma unroll
        for (int kh = 0; kh < 2; ++kh){
            bf16x8 af[4], bfr[2];
            #pragma unroll
            for (int i = 0; i < 4; ++i){
                int r = wm*64 + i*16 + lr;
                af[i] = *(const bf16x8*)(As + r*64 + (((kh*4 + quad) ^ (r & 7))*8));
            }
            #pragma unroll
            for (int j = 0; j < 2; ++j){
                int r = wn*32 + j*16 + lr;
                bfr[j] = *(const bf16x8*)(Bs + r*64 + (((kh*4 + quad) ^ (r & 7))*8));
            }
            #pragma unroll
            for (int i = 0; i < 4; ++i)
                #pragma unroll
                for (int j = 0; j < 2; ++j)
                    acc[i][j] = __builtin_amdgcn_mfma_f32_16x16x32_bf16(af[i], bfr[j], acc[i][j], 0, 0, 0);
        }
        __syncthreads();
    }

    #pragma unroll
    for (int i = 0; i < 4; ++i){
        #pragma unroll
        for (int j = 0; j < 2; ++j){
            const int row = rowT + wm*64 + i*16 + quad*4;
            const int col = colT + wn*32 + j*16 + lr;
            const float bb = bias ? bias[col] : 0.f;
            #pragma unroll
            for (int r = 0; r < 4; ++r){
                float val = acc[i][j][r] + bb;
                TC* cp = C + (size_t)(row + r)*ldc + col;
                if (EPI == 2) val = gelu_tanh(val);
                if (EPI == 1) val += *(float*)cp;
                if (EPI == 0 || EPI == 2) *(bf16*)cp = __float2bfloat16(val);
                else                      *(float*)cp = val;
            }
        }
    }
}

// ---------------- LayerNorm: wave per token ----------------
__global__ __launch_bounds__(256) void ln_wave(const float* __restrict__ x,
                                               const float* __restrict__ sc,
                                               const float* __restrict__ bs,
                                               bf16* __restrict__ y){
    const int tid = threadIdx.x, w = tid >> 6, l = tid & 63;
    const int t = blockIdx.x*4 + w;
    const float4* xr = (const float4*)(x + (size_t)t*CW);
    float4 a[3];
    #pragma unroll
    for (int i = 0; i < 3; ++i) a[i] = xr[l + 64*i];
    float s = 0.f;
    #pragma unroll
    for (int i = 0; i < 3; ++i) s += a[i].x + a[i].y + a[i].z + a[i].w;
    #pragma unroll
    for (int off = 1; off < 64; off <<= 1) s += __shfl_xor(s, off);
    const float m = s * (1.0f/768.0f);
    float vs = 0.f;
    #pragma unroll
    for (int i = 0; i < 3; ++i){
        float dx = a[i].x-m, dy = a[i].y-m, dz = a[i].z-m, dw = a[i].w-m;
        vs += dx*dx + dy*dy + dz*dz + dw*dw;
    }
    #pragma unroll
    for (int off = 1; off < 64; off <<= 1) vs += __shfl_xor(vs, off);
    const float rs = rsqrtf(vs*(1.0f/768.0f) + 1e-6f);
    const float4* scp = (const float4*)sc;
    const float4* bsp = (const float4*)bs;
    uint2* yr = (uint2*)(y + (size_t)t*CW);
    #pragma unroll
    for (int i = 0; i < 3; ++i){
        float4 sv = scp[l + 64*i], bv = bsp[l + 64*i];
        float r0 = (a[i].x-m)*rs*sv.x + bv.x;
        float r1 = (a[i].y-m)*rs*sv.y + bv.y;
        float r2 = (a[i].z-m)*rs*sv.z + bv.z;
        float r3 = (a[i].w-m)*rs*sv.w + bv.w;
        yr[l + 64*i] = make_uint2(bfpair(r0,r1), bfpair(r2,r3));
    }
}

// ---------------- RoPE apply on q and k inside packed qkv ----------------
__global__ void rope_qk(bf16* __restrict__ qkv, const float* __restrict__ rc){
    int idx = blockIdx.x*256 + threadIdx.x;   // NT*768 pairs
    int tok = idx / 768;
    int r = idx % 768;
    int rr, base;
    if (r < 384){ base = 0; rr = r; } else { base = 768; rr = r - 384; }
    int hh = rr >> 5, p = rr & 31;
    int l = tok % LTOK;
    float c, s;
    if (p < 16){ c = rc[l*16 + p];            s = rc[9216 + l*16 + p]; }
    else       { c = rc[18432 + l*16 + p-16]; s = rc[27648 + l*16 + p-16]; }
    bf16* pp = qkv + (size_t)tok*QKVW + base + hh*64 + 2*p;
    unsigned u = *(unsigned*)pp;
    bf16 lo = *(bf16*)&u; unsigned short hi16 = u >> 16; bf16 hi = *(bf16*)&hi16;
    float x = b2f(lo), y = b2f(hi);
    *(unsigned*)pp = bfpair(x*c - y*s, x*s + y*c);
}

// ---------------- V transpose ----------------
__global__ __launch_bounds__(256) void vtrans(const bf16* __restrict__ qkv, bf16* __restrict__ vT){
    __shared__ bf16 tile[64][72];
    const int t0 = blockIdx.x*64, hI = blockIdx.y, nI = blockIdx.z;
    const size_t base = ((size_t)nI*LTOK + t0)*QKVW + 1536 + hI*64;
    const int tid = threadIdx.x;
    #pragma unroll
    for (int i = 0; i < 2; ++i){
        int g = i*256 + tid, r = g >> 3, c = g & 7;
        *(uint4*)&tile[r][c*8] = *(const uint4*)(qkv + base + (size_t)r*QKVW + c*8);
    }
    __syncthreads();
    const size_t obase = ((size_t)(nI*NH + hI)*64)*576 + t0;
    #pragma unroll
    for (int i = 0; i < 2; ++i){
        int g = i*256 + tid, d = g >> 3, c = g & 7;
        bf16 tmp[8];
        #pragma unroll
        for (int j = 0; j < 8; ++j) tmp[j] = tile[c*8 + j][d];
        *(uint4*)(vT + obase + (size_t)d*576 + c*8) = *(uint4*)tmp;
    }
}

// ---------------- Flash attention ----------------
__global__ __launch_bounds__(256) void attn_flash(const bf16* __restrict__ qkv,
                                                  const bf16* __restrict__ vT,
                                                  bf16* __restrict__ o){
    __shared__ bf16 Ks[64*72];
    __shared__ bf16 Vs[64*72];
    __shared__ bf16 Ps[64*72];
    __shared__ float alph[64];
    __shared__ float lsum[64];
    const int tid = threadIdx.x;
    const int w = tid >> 6, l = tid & 63;
    const int quad = l >> 4, lr = l & 15;
    const int q0 = blockIdx.x * 64;
    const int hI = blockIdx.y, nI = blockIdx.z;
    const size_t tokBase = (size_t)nI * LTOK;
    const int off = hI * 64;
    const size_t vbase = ((size_t)(nI*NH + hI)*64)*576;

    bf16x8 qf[2];
    #pragma unroll
    for (int kh = 0; kh < 2; ++kh)
        qf[kh] = *(const bf16x8*)(qkv + (tokBase + q0 + w*16 + lr)*QKVW + off + kh*32 + quad*8);

    f32x4 oacc[4];
    #pragma unroll
    for (int j = 0; j < 4; ++j) oacc[j] = (f32x4){0.f,0.f,0.f,0.f};
    float m_run = -3.0e38f, l_run = 0.f;

    for (int ch = 0; ch < 9; ++ch){
        __syncthreads();
        #pragma unroll
        for (int i = 0; i < 2; ++i){
            int g = i*256 + tid, r = g >> 3, c = g & 7;
            *(uint4*)(Ks + r*72 + c*8) =
                *(const uint4*)(qkv + (tokBase + ch*64 + r)*QKVW + 768 + off + c*8);
        }
        #pragma unroll
        for (int i = 0; i < 2; ++i){
            int g = i*256 + tid, d = g >> 3, c = g & 7;
            *(uint4*)(Vs + d*72 + c*8) = *(const uint4*)(vT + vbase + (size_t)d*576 + ch*64 + c*8);
        }
        __syncthreads();

        f32x4 st[4];
        #pragma unroll
        for (int t = 0; t < 4; ++t){
            st[t] = (f32x4){0.f,0.f,0.f,0.f};
            #pragma unroll
            for (int kh = 0; kh < 2; ++kh){
                bf16x8 kf = *(const bf16x8*)(Ks + (t*16 + lr)*72 + kh*32 + quad*8);
                st[t] = __builtin_amdgcn_mfma_f32_16x16x32_bf16(kf, qf[kh], st[t], 0, 0, 0);
            }
        }
        float lm = -3.0e38f;
        #pragma unroll
        for (int t = 0; t < 4; ++t)
            #pragma unroll
            for (int r = 0; r < 4; ++r){
                st[t][r] *= 0.125f;
                lm = fmaxf(lm, st[t][r]);
            }
        lm = fmaxf(lm, __shfl_xor(lm, 16));
        lm = fmaxf(lm, __shfl_xor(lm, 32));
        float mn = fmaxf(m_run, lm);
        float alpha = __expf(m_run - mn);
        m_run = mn;
        float ls = 0.f;
        #pragma unroll
        for (int t = 0; t < 4; ++t)
            #pragma unroll
            for (int r = 0; r < 4; ++r){
                float p = __expf(st[t][r] - mn);
                st[t][r] = p; ls += p;
            }
        ls += __shfl_xor(ls, 16);
        ls += __shfl_xor(ls, 32);
        l_run = l_run*alpha + ls;
        if ((tid & 48) == 0) alph[w*16 + lr] = alpha;
        #pragma unroll
        for (int t = 0; t < 4; ++t)
            #pragma unroll
            for (int r = 0; r < 4; ++r)
                Ps[(w*16 + lr)*72 + t*16 + quad*4 + r] = __float2bfloat16(st[t][r]);
        float af[4];
        #pragma unroll
        for (int r = 0; r < 4; ++r) af[r] = alph[w*16 + quad*4 + r];
        #pragma unroll
        for (int j = 0; j < 4; ++j)
            #pragma unroll
            for (int r = 0; r < 4; ++r) oacc[j][r] *= af[r];
        #pragma unroll
        for (int kh = 0; kh < 2; ++kh){
            bf16x8 pf = *(const bf16x8*)(Ps + (w*16 + lr)*72 + kh*32 + quad*8);
            #pragma unroll
            for (int j = 0; j < 4; ++j){
                bf16x8 vf = *(const bf16x8*)(Vs + (j*16 + lr)*72 + kh*32 + quad*8);
                oacc[j] = __builtin_amdgcn_mfma_f32_16x16x32_bf16(pf, vf, oacc[j], 0, 0, 0);
            }
        }
    }

    if ((tid & 48) == 0) lsum[w*16 + lr] = l_run;
    float linv[4];
    #pragma unroll
    for (int r = 0; r < 4; ++r) linv[r] = 1.0f / lsum[w*16 + quad*4 + r];
    #pragma unroll
    for (int j = 0; j < 4; ++j)
        #pragma unroll
        for (int r = 0; r < 4; ++r)
            o[(tokBase + q0 + w*16 + quad*4 + r)*CW + off + j*16 + lr] =
                __float2bfloat16(oacc[j][r] * linv[r]);
}

// ---------------- final mean ----------------
__global__ void mean_kernel(const bf16* __restrict__ y, float* __restrict__ out){
    int c = blockIdx.x*256 + threadIdx.x;
    int n = blockIdx.y;
    float s = 0.f;
    for (int l = 0; l < LTOK; ++l) s += b2f(y[((size_t)n*LTOK + l)*CW + c]);
    out[n*CW + c] = s * (1.0f/576.0f);
}

extern "C" void kernel_launch(void* const* d_in, const int* in_sizes, int n_in,
                              void* d_out, int out_size, void* d_ws, size_t ws_size,
                              hipStream_t stream){
    const float* image = (const float*)d_in[0];
    const float* convk = (const float*)d_in[1];
    const float* convb = (const float*)d_in[2];
    const float* ln1s  = (const float*)d_in[3];
    const float* ln1b  = (const float*)d_in[4];
    const float* wq    = (const float*)d_in[5];
    const float* bq    = (const float*)d_in[6];
    const float* wk    = (const float*)d_in[7];
    const float* bk    = (const float*)d_in[8];
    const float* wv    = (const float*)d_in[9];
    const float* bv    = (const float*)d_in[10];
    const float* wo    = (const float*)d_in[11];
    const float* bo    = (const float*)d_in[12];
    const float* ln2s  = (const float*)d_in[13];
    const float* ln2b  = (const float*)d_in[14];
    const float* w1    = (const float*)d_in[15];
    const float* b1    = (const float*)d_in[16];
    const float* w2    = (const float*)d_in[17];
    const float* b2    = (const float*)d_in[18];
    const float* lnfs  = (const float*)d_in[19];
    const float* lnfb  = (const float*)d_in[20];
    float* out = (float*)d_out;

    const size_t u = (size_t)NT*CW;
    float* ws    = (float*)d_ws;
    float* ropeC = ws;
    float* bqkvA = ws + 36864;
    float* x     = bqkvA + 4*QKVW;
    bf16*  y     = (bf16*)(x + u);
    bf16*  qkv   = y + u;
    bf16*  o     = qkv + (size_t)NT*QKVW;
    bf16*  h     = o + u;
    bf16*  vT    = h + (size_t)NT*MLPW;
    bf16*  convT = vT + u;
    bf16*  wqkvT = convT + 589824;
    bf16*  woT   = wqkvT + (size_t)4*QKVW*CW;
    bf16*  w1T   = woT + (size_t)4*CW*CW;
    bf16*  w2T   = w1T + (size_t)4*CW*MLPW;

    rope_cache_kernel<<<36, 256, 0, stream>>>(ropeC);
    patch_gather<<<(NT*CW)/256, 256, 0, stream>>>(image, y);
    bias_pack<<<36, 256, 0, stream>>>(bq, bk, bv, bqkvA);
    wtrans_b<<<dim3(24,24,1), 256, 0, stream>>>(convk, convT, CW, CW, 0, 0);
    wtrans_b<<<dim3(24,24,4), 256, 0, stream>>>(wq, wqkvT,           CW, CW, (size_t)CW*CW, (size_t)QKVW*CW);
    wtrans_b<<<dim3(24,24,4), 256, 0, stream>>>(wk, wqkvT + 589824,  CW, CW, (size_t)CW*CW, (size_t)QKVW*CW);
    wtrans_b<<<dim3(24,24,4), 256, 0, stream>>>(wv, wqkvT + 1179648, CW, CW, (size_t)CW*CW, (size_t)QKVW*CW);
    wtrans_b<<<dim3(24,24,4), 256, 0, stream>>>(wo, woT,             CW, CW, (size_t)CW*CW, (size_t)CW*CW);
    wtrans_b<<<dim3(96,24,4), 256, 0, stream>>>(w1, w1T,  CW, MLPW, (size_t)CW*MLPW, (size_t)CW*MLPW);
    wtrans_b<<<dim3(24,96,4), 256, 0, stream>>>(w2, w2T, MLPW,  CW, (size_t)CW*MLPW, (size_t)CW*MLPW);

    gemm_a<3,float><<<dim3(12,36), 256, 0, stream>>>(y, CW, convT, CW, convb, x, CW, CW);

    for (int l = 0; l < DEPTH; ++l){
        ln_wave<<<NT/4, 256, 0, stream>>>(x, ln1s + l*CW, ln1b + l*CW, y);
        gemm_a<0,bf16><<<dim3(36,36), 256, 0, stream>>>(y, CW, wqkvT + (size_t)l*QKVW*CW, CW,
                                                        bqkvA + l*QKVW, qkv, QKVW, CW);
        rope_qk<<<(NT*768)/256, 256, 0, stream>>>(qkv, ropeC);
        vtrans<<<dim3(9, NH, NBATCH), 256, 0, stream>>>(qkv, vT);
        attn_flash<<<dim3(9, NH, NBATCH), 256, 0, stream>>>(qkv, vT, o);
        gemm_a<1,float><<<dim3(12,36), 256, 0, stream>>>(o, CW, woT + (size_t)l*CW*CW, CW,
                                                         bo + l*CW, x, CW, CW);
        ln_wave<<<NT/4, 256, 0, stream>>>(x, ln2s + l*CW, ln2b + l*CW, y);
        gemm_a<2,bf16><<<dim3(48,36), 256, 0, stream>>>(y, CW, w1T + (size_t)l*CW*MLPW, CW,
                                                        b1 + l*MLPW, h, MLPW, CW);
        gemm_a<1,float><<<dim3(12,36), 256, 0, stream>>>(h, MLPW, w2T + (size_t)l*CW*MLPW, MLPW,
                                                         b2 + l*CW, x, CW, MLPW);
    }
    ln_wave<<<NT/4, 256, 0, stream>>>(x, lnfs, lnfb, y);
    mean_kernel<<<dim3(3, NBATCH), 256, 0, stream>>>(y, out);
}